// Round 13
// baseline (1077.329 us; speedup 1.0000x reference)
//
#include <hip/hip_runtime.h>
#include <hip/hip_bf16.h>
#include <math.h>

#define TB 16
#define TS 512
#define TF 512
#define TH 8
#define TFF 2048
#define TL 3

typedef unsigned short u16;
typedef short bf16x8 __attribute__((ext_vector_type(8)));
typedef float f32x4 __attribute__((ext_vector_type(4)));

__device__ __forceinline__ u16 f2b(float f) {
    __hip_bfloat16 h = __float2bfloat16(f);
    return *reinterpret_cast<u16*>(&h);
}
__device__ __forceinline__ float b2f(u16 u) {
    unsigned int v = ((unsigned int)u) << 16;
    return __builtin_bit_cast(float, v);
}

__device__ __forceinline__ void gload_lds16(const void* g, void* l) {
    __builtin_amdgcn_global_load_lds(
        (const __attribute__((address_space(1))) unsigned int*)g,
        (__attribute__((address_space(3))) unsigned int*)l, 16, 0, 0);
}

// ---------------------------------------------------------------------------
// Batched transpose + fp32->bf16: src z matrices K x N (row-major) -> dst N x K
// ---------------------------------------------------------------------------
__global__ __launch_bounds__(256) void k_transpose_w(
    const float* __restrict__ src, u16* __restrict__ dst, int K, int N)
{
    __shared__ float tile[32][33];
    const int z = blockIdx.z;
    src += (size_t)z * K * N;
    dst += (size_t)z * K * N;
    const int n0 = blockIdx.x * 32, k0 = blockIdx.y * 32;
    const int tx = threadIdx.x & 31, ty = threadIdx.x >> 5;  // 32 x 8
    #pragma unroll
    for (int i = 0; i < 32; i += 8)
        tile[ty + i][tx] = src[(size_t)(k0 + ty + i) * N + n0 + tx];
    __syncthreads();
    #pragma unroll
    for (int i = 0; i < 32; i += 8)
        dst[(size_t)(n0 + ty + i) * K + k0 + tx] = f2b(tile[tx][ty + i]);
}

// ---------------------------------------------------------------------------
// fp32 -> bf16 convert (vectorized by 4)
// ---------------------------------------------------------------------------
__global__ __launch_bounds__(256) void k_cvt(
    const float* __restrict__ src, u16* __restrict__ d16, int n4)
{
    const int i = blockIdx.x * 256 + threadIdx.x;
    if (i >= n4) return;
    float4 v = ((const float4*)src)[i];
    ushort4 p;
    p.x = f2b(v.x); p.y = f2b(v.y); p.z = f2b(v.z); p.w = f2b(v.w);
    ((ushort4*)d16)[i] = p;
}

// ---------------------------------------------------------------------------
// 16-wave (1024-thread) 256x256 bf16 GEMM, BK=64. 4 waves/SIMD on one CU.
// Waves 4x4; per-wave 64x64 output (4x4 frags, 64 VGPR acc).
// 2-buffer LDS (128 KB), counted vmcnt(4) gate (NL=4 loads/wave/tile),
// stage(t+2) after all reads of buf[cur]. XCD-chunk block swizzle.
// EPI 1: +bias,gelu->bf16; EPI 3: scatter q/k; V via per-wave LDS transpose.
// ---------------------------------------------------------------------------
template<int EPI>
__global__ __launch_bounds__(1024, 1) void k_g16(
    const u16* __restrict__ A, const u16* __restrict__ A2, int asplit,
    const u16* __restrict__ BT,
    const float* __restrict__ bias,
    u16* __restrict__ outb,
    u16* __restrict__ out_k, u16* __restrict__ out_v,
    int N, int K, int ldo, int coloff)
{
    constexpr int BM = 256, BN = 256;
    __shared__ __align__(16) u16 SH[2 * BM * 64 + 2 * BN * 64];   // 128 KB
    u16* Asm = SH;
    u16* Bsm = SH + 2 * BM * 64;

    const int gx = gridDim.x;
    int bid = blockIdx.y * gx + blockIdx.x;
    const int cpx = (gx * gridDim.y) >> 3;
    bid = (bid & 7) * cpx + (bid >> 3);
    const int bn = bid % gx, bm = bid / gx;

    const int t = threadIdx.x;
    const int w = t >> 6, l = t & 63;         // 16 waves
    const int wm = w >> 2, wn = w & 3;        // 4 x 4
    const int lhi = l >> 4, llo = l & 15;

    f32x4 acc[4][4];
    #pragma unroll
    for (int m = 0; m < 4; ++m)
        #pragma unroll
        for (int n = 0; n < 4; ++n)
            acc[m][n] = f32x4{0.f, 0.f, 0.f, 0.f};

    const u16* Asrc = (bn * BN < asplit) ? A : A2;
    const int lr = l >> 3;
    const int lcz = ((l & 7) ^ lr) * 8;       // inverse-swizzled source chunk
    const u16* Ag = Asrc + (size_t)(bm * BM + w * 8 + lr) * K + lcz;
    const u16* Bg = BT + (size_t)(bn * BN + w * 8 + lr) * K + lcz;

    auto stage = [&](int buf, int tt) {
        const int kofs = tt << 6;
        #pragma unroll
        for (int i = 0; i < 2; ++i)
            gload_lds16(Ag + (size_t)i * 128 * K + kofs,
                        Asm + buf * (BM * 64) + (i * 128 + w * 8) * 64);
        #pragma unroll
        for (int i = 0; i < 2; ++i)
            gload_lds16(Bg + (size_t)i * 128 * K + kofs,
                        Bsm + buf * (BN * 64) + (i * 128 + w * 8) * 64);
    };

    const int NT = K >> 6;
    stage(0, 0);
    stage(1, 1);
    for (int tt = 0; tt < NT; ++tt) {
        const int cur = tt & 1;
        if (tt + 1 < NT) asm volatile("s_waitcnt vmcnt(4)" ::: "memory");
        else             asm volatile("s_waitcnt vmcnt(0)" ::: "memory");
        __builtin_amdgcn_s_barrier();
        __builtin_amdgcn_sched_barrier(0);

        const u16* Ab = Asm + cur * (BM * 64);
        const u16* Bb = Bsm + cur * (BN * 64);
        bf16x8 af[4][2], bfr[4][2];
        #pragma unroll
        for (int m = 0; m < 4; ++m) {
            const int row = wm * 64 + m * 16 + llo;
            const int x = row & 7;
            af[m][0] = *(const bf16x8*)(Ab + row * 64 + ((lhi) ^ x) * 8);
            af[m][1] = *(const bf16x8*)(Ab + row * 64 + ((4 + lhi) ^ x) * 8);
        }
        #pragma unroll
        for (int n = 0; n < 4; ++n) {
            const int row = wn * 64 + n * 16 + llo;
            const int x = row & 7;
            bfr[n][0] = *(const bf16x8*)(Bb + row * 64 + ((lhi) ^ x) * 8);
            bfr[n][1] = *(const bf16x8*)(Bb + row * 64 + ((4 + lhi) ^ x) * 8);
        }
        asm volatile("s_waitcnt lgkmcnt(0)" ::: "memory");
        __builtin_amdgcn_sched_barrier(0);
        __builtin_amdgcn_s_barrier();          // all waves done reading buf[cur]
        if (tt + 2 < NT) stage(cur, tt + 2);
        __builtin_amdgcn_s_setprio(1);
        #pragma unroll
        for (int kk = 0; kk < 2; ++kk)
            #pragma unroll
            for (int m = 0; m < 4; ++m)
                #pragma unroll
                for (int n = 0; n < 4; ++n)
                    acc[m][n] = __builtin_amdgcn_mfma_f32_16x16x32_bf16(
                        af[m][kk], bfr[n][kk], acc[m][n], 0, 0, 0);
        __builtin_amdgcn_s_setprio(0);
        __builtin_amdgcn_sched_barrier(0);
    }

    const int colb = bn * BN + wn * 64;
    const int rowb = bm * BM + wm * 64 + lhi * 4;
    const int c0w = coloff + colb;

    if constexpr (EPI == 3) {
        if (c0w >= 1024) {
            // ---- V region: per-wave 64s x 64d transpose via LDS (SH dead) ----
            __syncthreads();
            u16* tb = SH + w * 4096;    // 8 KB per wave, 16 waves = 128 KB
            #pragma unroll
            for (int n = 0; n < 4; ++n) {
                const int dl = n * 16 + llo;
                const float bv = bias[colb + n * 16 + llo];
                #pragma unroll
                for (int m = 0; m < 4; ++m) {
                    ushort4 pk;
                    #pragma unroll
                    for (int r = 0; r < 4; ++r)
                        ((u16*)&pk)[r] = f2b(acc[m][n][r] + bv);
                    const int slc = m * 2 + (lhi >> 1);
                    const int addr = dl * 64 + ((slc ^ (dl & 7)) << 3) + ((lhi & 1) << 2);
                    *(ushort4*)(tb + addr) = pk;
                }
            }
            asm volatile("s_waitcnt lgkmcnt(0)" ::: "memory");
            __builtin_amdgcn_sched_barrier(0);
            const int sbase = bm * BM + wm * 64;
            const int bidx = sbase >> 9;
            const int srem = sbase & 511;
            const int hh = (c0w >> 6) & 7;
            u16* vo = out_v + ((size_t)bidx * 8 + hh) * 32768 + srem;
            const int cchunk = l & 7;
            #pragma unroll
            for (int rr = 0; rr < 8; ++rr) {
                const int dl2 = (l >> 3) + rr * 8;
                const int ch = cchunk ^ (dl2 & 7);
                bf16x8 vv = *(const bf16x8*)(tb + dl2 * 64 + ch * 8);
                *(bf16x8*)(vo + (size_t)dl2 * 512 + cchunk * 8) = vv;
            }
            return;
        }
    }

    #pragma unroll
    for (int n = 0; n < 4; ++n) {
        const int col = colb + n * 16 + llo;
        const float bv = bias[col];
        #pragma unroll
        for (int m = 0; m < 4; ++m) {
            const int row = rowb + m * 16;
            if (EPI == 3) {
                float vv[4];
                #pragma unroll
                for (int r = 0; r < 4; ++r) vv[r] = acc[m][n][r] + bv;
                const int c = coloff + col;
                if ((c >> 9) == 0) {
                    #pragma unroll
                    for (int r = 0; r < 4; ++r)
                        outb[(size_t)(row + r) * 512 + c] = f2b(vv[r]);
                } else {
                    const int hh = (c >> 6) & 7, d = c & 63;
                    #pragma unroll
                    for (int r = 0; r < 4; ++r) {
                        const int rr = row + r;
                        out_k[((size_t)(rr >> 9) * 8 + hh) * 32768 + (rr & 511) * 64 + d] = f2b(vv[r]);
                    }
                }
            } else {
                #pragma unroll
                for (int r = 0; r < 4; ++r) {
                    float v = acc[m][n][r] + bv;
                    v = 0.5f * v * (1.f + erff(v * 0.70710678118654752f));
                    outb[(size_t)(row + r) * ldo + coloff + col] = f2b(v);
                }
            }
        }
    }
}

// ---------------------------------------------------------------------------
// 8-wave bf16 GEMM (128x128, BK=64): 2-buffer LDS, counted vmcnt, stage(t+2).
// Used for wo and ff2. EPI 2: +bias,+bf16 resid->bf16.
// ---------------------------------------------------------------------------
template<int EPI>
__global__ __launch_bounds__(512, 2) void k_g8(
    const u16* __restrict__ A,
    const u16* __restrict__ BT,
    const float* __restrict__ bias, const u16* __restrict__ residb,
    u16* __restrict__ outb,
    int N, int K, int ldo, int coloff)
{
    constexpr int BM = 128, BN = 128;
    constexpr int NFB = 2;
    __shared__ __align__(16) u16 SH[2 * BM * 64 + 2 * BN * 64];
    u16* Asm = SH;
    u16* Bsm = SH + 2 * BM * 64;

    const int gx = gridDim.x;
    int bid = blockIdx.y * gx + blockIdx.x;
    const int cpx = (gx * gridDim.y) >> 3;
    bid = (bid & 7) * cpx + (bid >> 3);
    const int bn = bid % gx, bm = bid / gx;

    const int t = threadIdx.x;
    const int w = t >> 6, l = t & 63;
    const int wm = w >> 2, wn = w & 3;
    const int lhi = l >> 4, llo = l & 15;

    f32x4 acc[4][NFB];
    #pragma unroll
    for (int m = 0; m < 4; ++m)
        #pragma unroll
        for (int n = 0; n < NFB; ++n)
            acc[m][n] = f32x4{0.f, 0.f, 0.f, 0.f};

    const int lr = l >> 3;
    const int lcz = ((l & 7) ^ lr) * 8;
    const u16* Ag = A + (size_t)(bm * BM + w * 8 + lr) * K + lcz;
    const u16* Bg = BT + (size_t)(bn * BN + w * 8 + lr) * K + lcz;

    auto stage = [&](int buf, int tt) {
        const int kofs = tt << 6;
        #pragma unroll
        for (int i = 0; i < 2; ++i)
            gload_lds16(Ag + (size_t)i * 64 * K + kofs,
                        Asm + buf * (BM * 64) + (i * 64 + w * 8) * 64);
        #pragma unroll
        for (int i = 0; i < 2; ++i)
            gload_lds16(Bg + (size_t)i * 64 * K + kofs,
                        Bsm + buf * (BN * 64) + (i * 64 + w * 8) * 64);
    };

    const int NT = K >> 6;
    stage(0, 0);
    stage(1, 1);
    for (int tt = 0; tt < NT; ++tt) {
        const int cur = tt & 1;
        if (tt + 1 < NT) asm volatile("s_waitcnt vmcnt(4)" ::: "memory");
        else             asm volatile("s_waitcnt vmcnt(0)" ::: "memory");
        __builtin_amdgcn_s_barrier();
        __builtin_amdgcn_sched_barrier(0);

        const u16* Ab = Asm + cur * (BM * 64);
        const u16* Bb = Bsm + cur * (BN * 64);
        bf16x8 af[4][2], bfr[NFB][2];
        #pragma unroll
        for (int m = 0; m < 4; ++m) {
            const int row = wm * 64 + m * 16 + llo;
            const int x = row & 7;
            af[m][0] = *(const bf16x8*)(Ab + row * 64 + ((lhi) ^ x) * 8);
            af[m][1] = *(const bf16x8*)(Ab + row * 64 + ((4 + lhi) ^ x) * 8);
        }
        #pragma unroll
        for (int n = 0; n < NFB; ++n) {
            const int row = wn * 32 + n * 16 + llo;
            const int x = row & 7;
            bfr[n][0] = *(const bf16x8*)(Bb + row * 64 + ((lhi) ^ x) * 8);
            bfr[n][1] = *(const bf16x8*)(Bb + row * 64 + ((4 + lhi) ^ x) * 8);
        }
        asm volatile("s_waitcnt lgkmcnt(0)" ::: "memory");
        __builtin_amdgcn_sched_barrier(0);
        __builtin_amdgcn_s_barrier();
        if (tt + 2 < NT) stage(cur, tt + 2);
        __builtin_amdgcn_s_setprio(1);
        #pragma unroll
        for (int kk = 0; kk < 2; ++kk)
            #pragma unroll
            for (int m = 0; m < 4; ++m)
                #pragma unroll
                for (int n = 0; n < NFB; ++n)
                    acc[m][n] = __builtin_amdgcn_mfma_f32_16x16x32_bf16(
                        af[m][kk], bfr[n][kk], acc[m][n], 0, 0, 0);
        __builtin_amdgcn_s_setprio(0);
        __builtin_amdgcn_sched_barrier(0);
    }

    const int colb = bn * BN + wn * 32;
    const int rowb = bm * BM + wm * 64 + lhi * 4;
    #pragma unroll
    for (int n = 0; n < NFB; ++n) {
        const int col = colb + n * 16 + llo;
        const float bv = bias[col];
        #pragma unroll
        for (int m = 0; m < 4; ++m) {
            const int row = rowb + m * 16;
            #pragma unroll
            for (int r = 0; r < 4; ++r) {
                float v = acc[m][n][r] + bv;
                const size_t off = (size_t)(row + r) * ldo + coloff + col;
                v += b2f(residb[off]);
                outb[off] = f2b(v);
            }
        }
    }
}

// ---------------------------------------------------------------------------
// Fused flash attention (unchanged).
// ---------------------------------------------------------------------------
template<int DEC>
__global__ __launch_bounds__(256) void k_attn(
    const u16* __restrict__ qb, const u16* __restrict__ kc,
    const u16* __restrict__ vtp, const int* __restrict__ lengths,
    u16* __restrict__ out)
{
    __shared__ __align__(16) u16 Ks[2][64 * 64];
    __shared__ __align__(16) u16 Vs[2][64 * 64];
    __shared__ __align__(16) u16 plds[4][16][64];
    __shared__ float alds[4][16];
    __shared__ float llds[4][16];
    const int qt = blockIdx.x;
    const int bh = blockIdx.y;
    const int b = bh >> 3;
    const int h = bh & 7;
    const int t = threadIdx.x, w = t >> 6, l = t & 63;
    const int lhi = l >> 4, llo = l & 15;
    const int len = lengths[b];
    const int qrow0 = qt * 64 + w * 16;
    const int q = qrow0 + llo;

    const u16* qp = qb + (size_t)(b * TS + q) * 512 + h * 64 + lhi * 8;
    bf16x8 qf0 = *(const bf16x8*)(qp);
    bf16x8 qf1 = *(const bf16x8*)(qp + 32);

    const u16* kb = kc  + (size_t)bh * 32768;
    const u16* vb = vtp + (size_t)bh * 32768;

    const int qlim = DEC ? min(max(q, 1), len) : len;
    const int limb = DEC ? min(qt * 64 + 63, len) : len;
    const int ktend = (limb + 63) >> 6;

    f32x4 o[4];
    #pragma unroll
    for (int g = 0; g < 4; ++g) o[g] = f32x4{0.f, 0.f, 0.f, 0.f};
    float mrun = -1e30f, lrun = 0.f;

    const float SC = 0.18033688011112042f;  // 0.125 * log2(e)

    const int sr = w * 8 + (l >> 3);
    const int sc = (((l & 7) ^ (sr & 7)) << 3);
    auto stage = [&](int buf, int ktt) {
        gload_lds16(kb + ((ktt * 64 + sr) << 6) + sc,        &Ks[buf][(w * 8) * 64]);
        gload_lds16(kb + ((ktt * 64 + 32 + sr) << 6) + sc,   &Ks[buf][(32 + w * 8) * 64]);
        gload_lds16(vb + (size_t)sr * 512 + ktt * 64 + sc,   &Vs[buf][(w * 8) * 64]);
        gload_lds16(vb + (size_t)(32 + sr) * 512 + ktt * 64 + sc, &Vs[buf][(32 + w * 8) * 64]);
    };

    stage(0, 0);
    for (int kt = 0; kt < ktend; ++kt) {
        const int cur = kt & 1;
        if (kt + 1 < ktend) {
            stage(cur ^ 1, kt + 1);
            asm volatile("s_waitcnt vmcnt(4)" ::: "memory");
        } else {
            asm volatile("s_waitcnt vmcnt(0)" ::: "memory");
        }
        __builtin_amdgcn_s_barrier();
        __builtin_amdgcn_sched_barrier(0);

        bf16x8 kf[4][2], vf[4][2];
        #pragma unroll
        for (int g = 0; g < 4; ++g) {
            const int row = g * 16 + llo;
            const int x = row & 7;
            kf[g][0] = *(const bf16x8*)&Ks[cur][row * 64 + ((lhi) ^ x) * 8];
            kf[g][1] = *(const bf16x8*)&Ks[cur][row * 64 + ((4 + lhi) ^ x) * 8];
            vf[g][0] = *(const bf16x8*)&Vs[cur][row * 64 + ((lhi) ^ x) * 8];
            vf[g][1] = *(const bf16x8*)&Vs[cur][row * 64 + ((4 + lhi) ^ x) * 8];
        }
        f32x4 s[4];
        #pragma unroll
        for (int g = 0; g < 4; ++g) {
            s[g] = f32x4{0.f, 0.f, 0.f, 0.f};
            s[g] = __builtin_amdgcn_mfma_f32_16x16x32_bf16(kf[g][0], qf0, s[g], 0, 0, 0);
            s[g] = __builtin_amdgcn_mfma_f32_16x16x32_bf16(kf[g][1], qf1, s[g], 0, 0, 0);
        }
        #pragma unroll
        for (int g = 0; g < 4; ++g) {
            const int key = kt * 64 + g * 16 + lhi * 4;
            #pragma unroll
            for (int r = 0; r < 4; ++r)
                s[g][r] = (key + r < qlim) ? s[g][r] * SC : -1e30f;
        }
        float tm = fmaxf(fmaxf(fmaxf(s[0][0], s[0][1]), fmaxf(s[0][2], s[0][3])),
                         fmaxf(fmaxf(s[1][0], s[1][1]), fmaxf(s[1][2], s[1][3])));
        tm = fmaxf(tm, fmaxf(fmaxf(fmaxf(s[2][0], s[2][1]), fmaxf(s[2][2], s[2][3])),
                             fmaxf(fmaxf(s[3][0], s[3][1]), fmaxf(s[3][2], s[3][3]))));
        tm = fmaxf(tm, __shfl_xor(tm, 16));
        tm = fmaxf(tm, __shfl_xor(tm, 32));
        const float mnew = fmaxf(mrun, tm);
        const float alpha = exp2f(mrun - mnew);
        mrun = mnew;
        float rs = 0.f;
        ushort4 pk[4];
        #pragma unroll
        for (int g = 0; g < 4; ++g) {
            #pragma unroll
            for (int r = 0; r < 4; ++r) {
                const float p = exp2f(s[g][r] - mnew);
                rs += p;
                ((u16*)&pk[g])[r] = f2b(p);
            }
        }
        rs += __shfl_xor(rs, 16);
        rs += __shfl_xor(rs, 32);
        lrun = lrun * alpha + rs;
        if (lhi == 0) alds[w][llo] = alpha;
        #pragma unroll
        for (int g = 0; g < 4; ++g) {
            const int chw = (g * 2 + (lhi >> 1)) ^ (llo & 7);
            *(ushort4*)((char*)&plds[w][0][0] + llo * 128 + chw * 16 + (lhi & 1) * 8) = pk[g];
        }
        const float4 av = *(const float4*)&alds[w][lhi * 4];
        #pragma unroll
        for (int g = 0; g < 4; ++g) {
            o[g][0] *= av.x; o[g][1] *= av.y; o[g][2] *= av.z; o[g][3] *= av.w;
        }
        #pragma unroll
        for (int ks = 0; ks < 2; ++ks) {
            const int chr = (ks * 4 + lhi) ^ (llo & 7);
            bf16x8 pa = *(const bf16x8*)((const char*)&plds[w][0][0] + llo * 128 + chr * 16);
            #pragma unroll
            for (int g = 0; g < 4; ++g)
                o[g] = __builtin_amdgcn_mfma_f32_16x16x32_bf16(pa, vf[g][ks], o[g], 0, 0, 0);
        }
        __builtin_amdgcn_sched_barrier(0);
        __builtin_amdgcn_s_barrier();
    }

    if (lhi == 0) llds[w][llo] = 1.f / lrun;
    __builtin_amdgcn_s_waitcnt(0);
    const float4 linv = *(const float4*)&llds[w][lhi * 4];
    #pragma unroll
    for (int g = 0; g < 4; ++g) {
        const int d = h * 64 + g * 16 + llo;
        #pragma unroll
        for (int r = 0; r < 4; ++r) {
            const int qq = qrow0 + lhi * 4 + r;
            out[(size_t)(b * TS + qq) * 512 + d] = f2b(o[g][r] * ((const float*)&linv)[r]);
        }
    }
}

// ---------------------------------------------------------------------------
// LayerNorm over F=512, bf16 in -> bf16 out; optional fused row-dot.
// ---------------------------------------------------------------------------
__global__ __launch_bounds__(256) void k_ln(
    const u16* __restrict__ in, const float* __restrict__ gam,
    const float* __restrict__ bet, u16* __restrict__ o16,
    const float* __restrict__ dotv, float* __restrict__ dotout)
{
    const int row = blockIdx.x * 4 + (threadIdx.x >> 6);
    const int l = threadIdx.x & 63;
    bf16x8 vin = *(const bf16x8*)(in + (size_t)row * 512 + l * 8);
    float x[8];
    #pragma unroll
    for (int i = 0; i < 8; ++i) x[i] = b2f((u16)vin[i]);
    float s = x[0] + x[1] + x[2] + x[3] + x[4] + x[5] + x[6] + x[7];
    #pragma unroll
    for (int off = 32; off; off >>= 1) s += __shfl_xor(s, off);
    const float mu = s * (1.f / 512.f);
    float v = 0.f;
    #pragma unroll
    for (int i = 0; i < 8; ++i) { const float d = x[i] - mu; v += d * d; }
    #pragma unroll
    for (int off = 32; off; off >>= 1) v += __shfl_xor(v, off);
    const float rstd = rsqrtf(v * (1.f / 512.f) + 1e-5f);
    float gg[8], bb[8];
    *(float4*)&gg[0] = *(const float4*)(gam + l * 8);
    *(float4*)&gg[4] = *(const float4*)(gam + l * 8 + 4);
    *(float4*)&bb[0] = *(const float4*)(bet + l * 8);
    *(float4*)&bb[4] = *(const float4*)(bet + l * 8 + 4);
    float y[8];
    #pragma unroll
    for (int i = 0; i < 8; ++i) y[i] = (x[i] - mu) * rstd * gg[i] + bb[i];
    ushort4 pk0, pk1;
    pk0.x = f2b(y[0]); pk0.y = f2b(y[1]); pk0.z = f2b(y[2]); pk0.w = f2b(y[3]);
    pk1.x = f2b(y[4]); pk1.y = f2b(y[5]); pk1.z = f2b(y[6]); pk1.w = f2b(y[7]);
    ushort4* o16p = (ushort4*)(o16 + (size_t)row * 512 + l * 8);
    o16p[0] = pk0; o16p[1] = pk1;
    if (dotv) {
        float wa[8];
        *(float4*)&wa[0] = *(const float4*)(dotv + l * 8);
        *(float4*)&wa[4] = *(const float4*)(dotv + l * 8 + 4);
        float ds = 0.f;
        #pragma unroll
        for (int i = 0; i < 8; ++i) ds += y[i] * wa[i];
        #pragma unroll
        for (int off = 32; off; off >>= 1) ds += __shfl_xor(ds, off);
        if (l == 0) dotout[row] = ds;
    }
}

// ---------------------------------------------------------------------------
__global__ __launch_bounds__(256) void k_ptr_out(
    const float* __restrict__ wq, const float* __restrict__ wk, float* __restrict__ out)
{
    const int bi = blockIdx.x;
    const int b = bi >> 9;
    const float wki = wk[bi];
    #pragma unroll
    for (int j = threadIdx.x; j < 512; j += 256) {
        float r = 0.f;
        if (j != 0) {
            const float z = (wq[b * 512 + j] + wki) * 0.044194173824159216f;
            r = 1.f / (1.f + __expf(-z));
        }
        out[(size_t)bi * 512 + j] = r;
    }
}

// ---------------------------------------------------------------------------
extern "C" void kernel_launch(void* const* d_in, const int* in_sizes, int n_in,
                              void* d_out, int out_size, void* d_ws, size_t ws_size,
                              hipStream_t stream)
{
    const float* emb = (const float*)d_in[0];
    const int* lengths = (const int*)d_in[1];
    struct Pw {
        const float *wqkv, *bqkv, *wo, *bo, *ln1g, *ln1b, *w1, *b1, *w2, *b2, *ln2g, *ln2b;
    } pp[2];
    for (int p = 0; p < 2; ++p) {
        const int base = 2 + p * 12;
        pp[p].wqkv = (const float*)d_in[base + 0];
        pp[p].bqkv = (const float*)d_in[base + 1];
        pp[p].wo   = (const float*)d_in[base + 2];
        pp[p].bo   = (const float*)d_in[base + 3];
        pp[p].ln1g = (const float*)d_in[base + 4];
        pp[p].ln1b = (const float*)d_in[base + 5];
        pp[p].w1   = (const float*)d_in[base + 6];
        pp[p].b1   = (const float*)d_in[base + 7];
        pp[p].w2   = (const float*)d_in[base + 8];
        pp[p].b2   = (const float*)d_in[base + 9];
        pp[p].ln2g = (const float*)d_in[base + 10];
        pp[p].ln2b = (const float*)d_in[base + 11];
    }
    const float* pwq = (const float*)d_in[26];
    const float* pwk = (const float*)d_in[27];

    char* ws = (char*)d_ws;
    auto alloc = [&](size_t bytes) {
        char* p = ws;
        ws += (bytes + 255) & ~(size_t)255;
        return p;
    };
    u16* wqkvT[2], *woT[2], *w1T[2], *w2T[2];
    for (int p = 0; p < 2; ++p) {
        wqkvT[p] = (u16*)alloc((size_t)TL * 1536 * 512 * 2);
        woT[p]   = (u16*)alloc((size_t)TL * 512 * 512 * 2);
        w1T[p]   = (u16*)alloc((size_t)TL * 2048 * 512 * 2);
        w2T[p]   = (u16*)alloc((size_t)TL * 512 * 2048 * 2);
    }
    const size_t MR = (size_t)TB * TS;  // 8192 rows
    u16*   emb16 = (u16*)alloc(MR * 512 * 2);
    u16*   x16   = (u16*)alloc(MR * 512 * 2);
    u16*   mem16 = (u16*)alloc(MR * 512 * 2);
    u16*   pre16 = (u16*)alloc(MR * 512 * 2);
    u16*   qbuf  = (u16*)alloc(MR * 512 * 2);
    u16*   kcb   = (u16*)alloc((size_t)TB * TH * 512 * 64 * 2);
    u16*   vtb   = (u16*)alloc((size_t)TB * TH * 64 * 512 * 2);
    u16*   att16 = (u16*)alloc(MR * 512 * 2);
    u16*   h16   = (u16*)alloc(MR * 2048 * 2);
    float* wqb   = (float*)alloc(MR * 4);
    float* wkb   = (float*)alloc(MR * 4);

    for (int p = 0; p < 2; ++p) {
        k_transpose_w<<<dim3(16, 16, 9), 256, 0, stream>>>(pp[p].wqkv, wqkvT[p], 512, 512);
        k_transpose_w<<<dim3(16, 16, 3), 256, 0, stream>>>(pp[p].wo, woT[p], 512, 512);
        k_transpose_w<<<dim3(64, 16, 3), 256, 0, stream>>>(pp[p].w1, w1T[p], 512, 2048);
        k_transpose_w<<<dim3(16, 64, 3), 256, 0, stream>>>(pp[p].w2, w2T[p], 2048, 512);
    }

    const int n4 = (int)(MR * 512 / 4);
    k_cvt<<<4096, 256, 0, stream>>>(emb, emb16, n4);

    // ---------------- encoder ----------------
    for (int i = 0; i < TL; ++i) {
        const u16* xin = (i == 0) ? emb16 : x16;
        k_g16<3><<<dim3(6, 32), 1024, 0, stream>>>(
            xin, xin, 1536, wqkvT[0] + (size_t)i * 1536 * 512, pp[0].bqkv + i * 1536,
            qbuf, kcb, vtb, 1536, 512, 1536, 0);
        k_attn<0><<<dim3(8, 128), 256, 0, stream>>>(qbuf, kcb, vtb, lengths, att16);
        k_g8<2><<<dim3(4, 64), 512, 0, stream>>>(
            att16, woT[0] + (size_t)i * 512 * 512, pp[0].bo + i * 512,
            xin, pre16, 512, 512, 512, 0);
        k_ln<<<2048, 256, 0, stream>>>(pre16, pp[0].ln1g + i * 512, pp[0].ln1b + i * 512,
                                       x16, nullptr, nullptr);
        k_g16<1><<<dim3(8, 32), 1024, 0, stream>>>(
            x16, x16, 2048, w1T[0] + (size_t)i * 2048 * 512, pp[0].b1 + i * 2048,
            h16, nullptr, nullptr, 2048, 512, 2048, 0);
        k_g8<2><<<dim3(4, 64), 512, 0, stream>>>(
            h16, w2T[0] + (size_t)i * 512 * 2048, pp[0].b2 + i * 512,
            x16, pre16, 512, 2048, 512, 0);
        if (i == TL - 1)
            k_ln<<<2048, 256, 0, stream>>>(pre16, pp[0].ln2g + i * 512, pp[0].ln2b + i * 512,
                                           mem16, pwk, wkb);
        else
            k_ln<<<2048, 256, 0, stream>>>(pre16, pp[0].ln2g + i * 512, pp[0].ln2b + i * 512,
                                           x16, nullptr, nullptr);
    }

    // ---------------- decoder ----------------
    for (int i = 0; i < TL; ++i) {
        const u16* yin = (i == 0) ? emb16 : x16;
        k_g16<3><<<dim3(6, 32), 1024, 0, stream>>>(
            yin, mem16, 512, wqkvT[1] + (size_t)i * 1536 * 512, pp[1].bqkv + i * 1536,
            qbuf, kcb, vtb, 1536, 512, 1536, 0);
        k_attn<1><<<dim3(8, 128), 256, 0, stream>>>(qbuf, kcb, vtb, lengths, att16);
        k_g8<2><<<dim3(4, 64), 512, 0, stream>>>(
            att16, woT[1] + (size_t)i * 512 * 512, pp[1].bo + i * 512,
            yin, pre16, 512, 512, 512, 0);
        k_ln<<<2048, 256, 0, stream>>>(pre16, pp[1].ln1g + i * 512, pp[1].ln1b + i * 512,
                                       x16, nullptr, nullptr);
        k_g16<1><<<dim3(8, 32), 1024, 0, stream>>>(
            x16, x16, 2048, w1T[1] + (size_t)i * 2048 * 512, pp[1].b1 + i * 2048,
            h16, nullptr, nullptr, 2048, 512, 2048, 0);
        k_g8<2><<<dim3(4, 64), 512, 0, stream>>>(
            h16, w2T[1] + (size_t)i * 512 * 2048, pp[1].b2 + i * 512,
            x16, pre16, 512, 2048, 512, 0);
        if (i == TL - 1)
            k_ln<<<2048, 256, 0, stream>>>(pre16, pp[1].ln2g + i * 512, pp[1].ln2b + i * 512,
                                           x16, pwq, wqb);
        else
            k_ln<<<2048, 256, 0, stream>>>(pre16, pp[1].ln2g + i * 512, pp[1].ln2b + i * 512,
                                           x16, nullptr, nullptr);
    }

    // ---------------- pointer head ----------------
    k_ptr_out<<<TB * TS, 256, 0, stream>>>(wqb, wkb, (float*)d_out);
}

// Round 14
// 841.436 us; speedup vs baseline: 1.2803x; 1.2803x over previous
//
#include <hip/hip_runtime.h>
#include <hip/hip_bf16.h>
#include <math.h>

#define TB 16
#define TS 512
#define TF 512
#define TH 8
#define TFF 2048
#define TL 3

typedef unsigned short u16;
typedef short bf16x8 __attribute__((ext_vector_type(8)));
typedef float f32x4 __attribute__((ext_vector_type(4)));

__device__ __forceinline__ u16 f2b(float f) {
    __hip_bfloat16 h = __float2bfloat16(f);
    return *reinterpret_cast<u16*>(&h);
}
__device__ __forceinline__ float b2f(u16 u) {
    unsigned int v = ((unsigned int)u) << 16;
    return __builtin_bit_cast(float, v);
}

__device__ __forceinline__ void gload_lds16(const void* g, void* l) {
    __builtin_amdgcn_global_load_lds(
        (const __attribute__((address_space(1))) unsigned int*)g,
        (__attribute__((address_space(3))) unsigned int*)l, 16, 0, 0);
}

// ---------------------------------------------------------------------------
// Batched transpose + fp32->bf16: src z matrices K x N (row-major) -> dst N x K
// ---------------------------------------------------------------------------
__global__ __launch_bounds__(256) void k_transpose_w(
    const float* __restrict__ src, u16* __restrict__ dst, int K, int N)
{
    __shared__ float tile[32][33];
    const int z = blockIdx.z;
    src += (size_t)z * K * N;
    dst += (size_t)z * K * N;
    const int n0 = blockIdx.x * 32, k0 = blockIdx.y * 32;
    const int tx = threadIdx.x & 31, ty = threadIdx.x >> 5;  // 32 x 8
    #pragma unroll
    for (int i = 0; i < 32; i += 8)
        tile[ty + i][tx] = src[(size_t)(k0 + ty + i) * N + n0 + tx];
    __syncthreads();
    #pragma unroll
    for (int i = 0; i < 32; i += 8)
        dst[(size_t)(n0 + ty + i) * K + k0 + tx] = f2b(tile[tx][ty + i]);
}

// ---------------------------------------------------------------------------
// fp32 -> bf16 convert (vectorized by 4)
// ---------------------------------------------------------------------------
__global__ __launch_bounds__(256) void k_cvt(
    const float* __restrict__ src, u16* __restrict__ d16, int n4)
{
    const int i = blockIdx.x * 256 + threadIdx.x;
    if (i >= n4) return;
    float4 v = ((const float4*)src)[i];
    ushort4 p;
    p.x = f2b(v.x); p.y = f2b(v.y); p.z = f2b(v.z); p.w = f2b(v.w);
    ((ushort4*)d16)[i] = p;
}

// ---------------------------------------------------------------------------
// QKV GEMM (round-10 fine-phase): BM=128 x BN=256, BK=64, 8 waves (2x4),
// 3-buffer LDS rotation, counted vmcnt(6) gate, stage(t+2) after gate barrier.
// Per K-tile: 4 phases {ds_read subtile -> barrier -> lgkm(0) -> setprio MFMA}.
// EPI 3: scatter q/k; V via wave-local LDS-bounce transpose.
// ---------------------------------------------------------------------------
template<int EPI>
__global__ __launch_bounds__(512, 1) void k_gf(
    const u16* __restrict__ A, const u16* __restrict__ A2, int asplit,
    const u16* __restrict__ BT,
    const float* __restrict__ bias,
    u16* __restrict__ outb,
    u16* __restrict__ out_k, u16* __restrict__ out_v,
    int N, int K, int ldo, int coloff)
{
    constexpr int BN = 256;
    constexpr int NFB = 4;
    __shared__ __align__(16) u16 SH[3 * 128 * 64 + 3 * BN * 64];
    u16* Asm = SH;
    u16* Bsm = SH + 3 * 128 * 64;

    const int gx = gridDim.x;
    int bid = blockIdx.y * gx + blockIdx.x;
    const int cpx = (gx * gridDim.y) >> 3;
    bid = (bid & 7) * cpx + (bid >> 3);
    const int bn = bid % gx, bm = bid / gx;

    const int t = threadIdx.x;
    const int w = t >> 6, l = t & 63;
    const int wm = w >> 2, wn = w & 3;
    const int lhi = l >> 4, llo = l & 15;

    f32x4 acc[4][NFB];
    #pragma unroll
    for (int m = 0; m < 4; ++m)
        #pragma unroll
        for (int n = 0; n < NFB; ++n)
            acc[m][n] = f32x4{0.f, 0.f, 0.f, 0.f};

    const u16* Asrc = (bn * BN < asplit) ? A : A2;
    const int lr = l >> 3;
    const int lcz = ((l & 7) ^ lr) * 8;
    const u16* Ag = Asrc + (size_t)(bm * 128 + w * 8 + lr) * K + lcz;
    const u16* Bg = BT + (size_t)(bn * BN + w * 8 + lr) * K + lcz;

    auto stage = [&](int buf, int tt) {
        const int kofs = tt << 6;
        gload_lds16(Ag + kofs,          Asm + buf * 8192 + (w * 8) * 64);
        gload_lds16(Ag + 64 * K + kofs, Asm + buf * 8192 + (64 + w * 8) * 64);
        #pragma unroll
        for (int i = 0; i < 4; ++i)
            gload_lds16(Bg + (size_t)i * 64 * K + kofs,
                        Bsm + buf * (BN * 64) + (i * 64 + w * 8) * 64);
    };

    const int NT = K >> 6;
    stage(0, 0);
    stage(1, 1);
    int cur = 0;
    for (int tt = 0; tt < NT; ++tt) {
        if (tt + 1 < NT) asm volatile("s_waitcnt vmcnt(6)" ::: "memory");
        else             asm volatile("s_waitcnt vmcnt(0)" ::: "memory");
        __builtin_amdgcn_s_barrier();
        __builtin_amdgcn_sched_barrier(0);
        if (tt + 2 < NT) {
            int nb = cur + 2; if (nb >= 3) nb -= 3;
            stage(nb, tt + 2);
        }

        const u16* Ab = Asm + cur * 8192;
        const u16* Bb = Bsm + cur * (BN * 64);
        bf16x8 af[4][2], bfr[NFB][2];

        #pragma unroll
        for (int kk = 0; kk < 2; ++kk) {
            #pragma unroll
            for (int mh = 0; mh < 2; ++mh) {
                #pragma unroll
                for (int mi = 0; mi < 2; ++mi) {
                    const int m = mh * 2 + mi;
                    const int row = wm * 64 + m * 16 + llo;
                    const int x = row & 7;
                    af[m][kk] = *(const bf16x8*)(Ab + row * 64 + ((kk * 4 + lhi) ^ x) * 8);
                }
                if (mh == 0) {
                    #pragma unroll
                    for (int n = 0; n < NFB; ++n) {
                        const int row = wn * 64 + n * 16 + llo;
                        const int x = row & 7;
                        bfr[n][kk] = *(const bf16x8*)(Bb + row * 64 + ((kk * 4 + lhi) ^ x) * 8);
                    }
                }
                __builtin_amdgcn_s_barrier();
                asm volatile("s_waitcnt lgkmcnt(0)" ::: "memory");
                __builtin_amdgcn_sched_barrier(0);
                __builtin_amdgcn_s_setprio(1);
                #pragma unroll
                for (int mi = 0; mi < 2; ++mi) {
                    const int m = mh * 2 + mi;
                    #pragma unroll
                    for (int n = 0; n < NFB; ++n)
                        acc[m][n] = __builtin_amdgcn_mfma_f32_16x16x32_bf16(
                            af[m][kk], bfr[n][kk], acc[m][n], 0, 0, 0);
                }
                __builtin_amdgcn_s_setprio(0);
                __builtin_amdgcn_sched_barrier(0);
            }
        }
        ++cur; if (cur >= 3) cur = 0;
    }

    const int colb = bn * BN + wn * 64;
    const int rowb = bm * 128 + wm * 64 + lhi * 4;
    const int c0w = coloff + colb;

    if constexpr (EPI == 3) {
        if (c0w >= 1024) {
            __builtin_amdgcn_s_barrier();   // all waves done reading LDS
            u16* tb = SH + w * 4096;
            #pragma unroll
            for (int n = 0; n < 4; ++n) {
                const int dl = n * 16 + llo;
                const float bv = bias[colb + n * 16 + llo];
                #pragma unroll
                for (int m = 0; m < 4; ++m) {
                    ushort4 pk;
                    #pragma unroll
                    for (int r = 0; r < 4; ++r)
                        ((u16*)&pk)[r] = f2b(acc[m][n][r] + bv);
                    const int slc = m * 2 + (lhi >> 1);
                    const int addr = dl * 64 + ((slc ^ (dl & 7)) << 3) + ((lhi & 1) << 2);
                    *(ushort4*)(tb + addr) = pk;
                }
            }
            asm volatile("s_waitcnt lgkmcnt(0)" ::: "memory");
            __builtin_amdgcn_sched_barrier(0);
            const int sbase = bm * 128 + wm * 64;
            const int bidx = sbase >> 9;
            const int srem = sbase & 511;
            const int hh = (c0w >> 6) & 7;
            u16* vo = out_v + ((size_t)bidx * 8 + hh) * 32768 + srem;
            const int cchunk = l & 7;
            #pragma unroll
            for (int rr = 0; rr < 8; ++rr) {
                const int dl2 = (l >> 3) + rr * 8;
                const int ch = cchunk ^ (dl2 & 7);
                bf16x8 vv = *(const bf16x8*)(tb + dl2 * 64 + ch * 8);
                *(bf16x8*)(vo + (size_t)dl2 * 512 + cchunk * 8) = vv;
            }
            return;
        }
    }

    #pragma unroll
    for (int n = 0; n < NFB; ++n) {
        const int col = colb + n * 16 + llo;
        const float bv = bias[col];
        #pragma unroll
        for (int m = 0; m < 4; ++m) {
            const int row = rowb + m * 16;
            float vv[4];
            #pragma unroll
            for (int r = 0; r < 4; ++r) vv[r] = acc[m][n][r] + bv;
            const int c = coloff + col;
            if ((c >> 9) == 0) {
                #pragma unroll
                for (int r = 0; r < 4; ++r)
                    outb[(size_t)(row + r) * 512 + c] = f2b(vv[r]);
            } else {
                const int hh = (c >> 6) & 7, d = c & 63;
                #pragma unroll
                for (int r = 0; r < 4; ++r) {
                    const int rr = row + r;
                    out_k[((size_t)(rr >> 9) * 8 + hh) * 32768 + (rr & 511) * 64 + d] = f2b(vv[r]);
                }
            }
        }
    }
}

// ---------------------------------------------------------------------------
// 8-wave bf16 GEMM (round-11): tile BM x BN (256x256 or 128x128), BK=64,
// 2-buffer LDS, counted vmcnt gate, stage(t+2) after reads. Used for
// ff1 (256x256, EPI 1) and wo/ff2 (128x128, EPI 2).
// ---------------------------------------------------------------------------
template<int EPI, int BM, int BN>
__global__ __launch_bounds__(512, 2) void k_g8(
    const u16* __restrict__ A,
    const u16* __restrict__ BT,
    const float* __restrict__ bias, const u16* __restrict__ residb,
    u16* __restrict__ outb,
    int N, int K, int ldo, int coloff)
{
    constexpr int WN  = (BM == 256) ? 2 : 4;
    constexpr int CS  = BN / WN;
    constexpr int NFB = CS / 16;
    constexpr int NLA = BM / 64, NLB = BN / 64;
    constexpr int NL  = NLA + NLB;
    __shared__ __align__(16) u16 SH[2 * BM * 64 + 2 * BN * 64];
    u16* Asm = SH;
    u16* Bsm = SH + 2 * BM * 64;

    const int gx = gridDim.x;
    int bid = blockIdx.y * gx + blockIdx.x;
    const int cpx = (gx * gridDim.y) >> 3;
    bid = (bid & 7) * cpx + (bid >> 3);
    const int bn = bid % gx, bm = bid / gx;

    const int t = threadIdx.x;
    const int w = t >> 6, l = t & 63;
    const int wm = w / WN, wn = w % WN;
    const int lhi = l >> 4, llo = l & 15;

    f32x4 acc[4][NFB];
    #pragma unroll
    for (int m = 0; m < 4; ++m)
        #pragma unroll
        for (int n = 0; n < NFB; ++n)
            acc[m][n] = f32x4{0.f, 0.f, 0.f, 0.f};

    const int lr = l >> 3;
    const int lcz = ((l & 7) ^ lr) * 8;
    const u16* Ag = A + (size_t)(bm * BM + w * 8 + lr) * K + lcz;
    const u16* Bg = BT + (size_t)(bn * BN + w * 8 + lr) * K + lcz;

    auto stage = [&](int buf, int tt) {
        const int kofs = tt << 6;
        #pragma unroll
        for (int i = 0; i < NLA; ++i)
            gload_lds16(Ag + (size_t)i * 64 * K + kofs,
                        Asm + buf * (BM * 64) + (i * 64 + w * 8) * 64);
        #pragma unroll
        for (int i = 0; i < NLB; ++i)
            gload_lds16(Bg + (size_t)i * 64 * K + kofs,
                        Bsm + buf * (BN * 64) + (i * 64 + w * 8) * 64);
    };

    const int NT = K >> 6;
    stage(0, 0);
    stage(1, 1);
    for (int tt = 0; tt < NT; ++tt) {
        const int cur = tt & 1;
        if (tt + 1 < NT) {
            if constexpr (NL == 8) asm volatile("s_waitcnt vmcnt(8)" ::: "memory");
            else                   asm volatile("s_waitcnt vmcnt(4)" ::: "memory");
        } else {
            asm volatile("s_waitcnt vmcnt(0)" ::: "memory");
        }
        __builtin_amdgcn_s_barrier();
        __builtin_amdgcn_sched_barrier(0);

        const u16* Ab = Asm + cur * (BM * 64);
        const u16* Bb = Bsm + cur * (BN * 64);
        bf16x8 af[4][2], bfr[NFB][2];
        #pragma unroll
        for (int m = 0; m < 4; ++m) {
            const int row = wm * 64 + m * 16 + llo;
            const int x = row & 7;
            af[m][0] = *(const bf16x8*)(Ab + row * 64 + ((lhi) ^ x) * 8);
            af[m][1] = *(const bf16x8*)(Ab + row * 64 + ((4 + lhi) ^ x) * 8);
        }
        #pragma unroll
        for (int n = 0; n < NFB; ++n) {
            const int row = wn * CS + n * 16 + llo;
            const int x = row & 7;
            bfr[n][0] = *(const bf16x8*)(Bb + row * 64 + ((lhi) ^ x) * 8);
            bfr[n][1] = *(const bf16x8*)(Bb + row * 64 + ((4 + lhi) ^ x) * 8);
        }
        asm volatile("s_waitcnt lgkmcnt(0)" ::: "memory");
        __builtin_amdgcn_sched_barrier(0);
        __builtin_amdgcn_s_barrier();
        if (tt + 2 < NT) stage(cur, tt + 2);
        __builtin_amdgcn_s_setprio(1);
        #pragma unroll
        for (int kk = 0; kk < 2; ++kk)
            #pragma unroll
            for (int m = 0; m < 4; ++m)
                #pragma unroll
                for (int n = 0; n < NFB; ++n)
                    acc[m][n] = __builtin_amdgcn_mfma_f32_16x16x32_bf16(
                        af[m][kk], bfr[n][kk], acc[m][n], 0, 0, 0);
        __builtin_amdgcn_s_setprio(0);
        __builtin_amdgcn_sched_barrier(0);
    }

    const int colb = bn * BN + wn * CS;
    const int rowb = bm * BM + wm * 64 + lhi * 4;
    #pragma unroll
    for (int n = 0; n < NFB; ++n) {
        const int col = colb + n * 16 + llo;
        const float bv = bias[col];
        #pragma unroll
        for (int m = 0; m < 4; ++m) {
            const int row = rowb + m * 16;
            #pragma unroll
            for (int r = 0; r < 4; ++r) {
                float v = acc[m][n][r] + bv;
                const size_t off = (size_t)(row + r) * ldo + coloff + col;
                if (EPI == 1) {
                    v = 0.5f * v * (1.f + erff(v * 0.70710678118654752f));
                    outb[off] = f2b(v);
                } else {  // EPI == 2
                    v += b2f(residb[off]);
                    outb[off] = f2b(v);
                }
            }
        }
    }
}

// ---------------------------------------------------------------------------
// Fused flash attention (unchanged).
// ---------------------------------------------------------------------------
template<int DEC>
__global__ __launch_bounds__(256) void k_attn(
    const u16* __restrict__ qb, const u16* __restrict__ kc,
    const u16* __restrict__ vtp, const int* __restrict__ lengths,
    u16* __restrict__ out)
{
    __shared__ __align__(16) u16 Ks[2][64 * 64];
    __shared__ __align__(16) u16 Vs[2][64 * 64];
    __shared__ __align__(16) u16 plds[4][16][64];
    __shared__ float alds[4][16];
    __shared__ float llds[4][16];
    const int qt = blockIdx.x;
    const int bh = blockIdx.y;
    const int b = bh >> 3;
    const int h = bh & 7;
    const int t = threadIdx.x, w = t >> 6, l = t & 63;
    const int lhi = l >> 4, llo = l & 15;
    const int len = lengths[b];
    const int qrow0 = qt * 64 + w * 16;
    const int q = qrow0 + llo;

    const u16* qp = qb + (size_t)(b * TS + q) * 512 + h * 64 + lhi * 8;
    bf16x8 qf0 = *(const bf16x8*)(qp);
    bf16x8 qf1 = *(const bf16x8*)(qp + 32);

    const u16* kb = kc  + (size_t)bh * 32768;
    const u16* vb = vtp + (size_t)bh * 32768;

    const int qlim = DEC ? min(max(q, 1), len) : len;
    const int limb = DEC ? min(qt * 64 + 63, len) : len;
    const int ktend = (limb + 63) >> 6;

    f32x4 o[4];
    #pragma unroll
    for (int g = 0; g < 4; ++g) o[g] = f32x4{0.f, 0.f, 0.f, 0.f};
    float mrun = -1e30f, lrun = 0.f;

    const float SC = 0.18033688011112042f;  // 0.125 * log2(e)

    const int sr = w * 8 + (l >> 3);
    const int sc = (((l & 7) ^ (sr & 7)) << 3);
    auto stage = [&](int buf, int ktt) {
        gload_lds16(kb + ((ktt * 64 + sr) << 6) + sc,        &Ks[buf][(w * 8) * 64]);
        gload_lds16(kb + ((ktt * 64 + 32 + sr) << 6) + sc,   &Ks[buf][(32 + w * 8) * 64]);
        gload_lds16(vb + (size_t)sr * 512 + ktt * 64 + sc,   &Vs[buf][(w * 8) * 64]);
        gload_lds16(vb + (size_t)(32 + sr) * 512 + ktt * 64 + sc, &Vs[buf][(32 + w * 8) * 64]);
    };

    stage(0, 0);
    for (int kt = 0; kt < ktend; ++kt) {
        const int cur = kt & 1;
        if (kt + 1 < ktend) {
            stage(cur ^ 1, kt + 1);
            asm volatile("s_waitcnt vmcnt(4)" ::: "memory");
        } else {
            asm volatile("s_waitcnt vmcnt(0)" ::: "memory");
        }
        __builtin_amdgcn_s_barrier();
        __builtin_amdgcn_sched_barrier(0);

        bf16x8 kf[4][2], vf[4][2];
        #pragma unroll
        for (int g = 0; g < 4; ++g) {
            const int row = g * 16 + llo;
            const int x = row & 7;
            kf[g][0] = *(const bf16x8*)&Ks[cur][row * 64 + ((lhi) ^ x) * 8];
            kf[g][1] = *(const bf16x8*)&Ks[cur][row * 64 + ((4 + lhi) ^ x) * 8];
            vf[g][0] = *(const bf16x8*)&Vs[cur][row * 64 + ((lhi) ^ x) * 8];
            vf[g][1] = *(const bf16x8*)&Vs[cur][row * 64 + ((4 + lhi) ^ x) * 8];
        }
        f32x4 s[4];
        #pragma unroll
        for (int g = 0; g < 4; ++g) {
            s[g] = f32x4{0.f, 0.f, 0.f, 0.f};
            s[g] = __builtin_amdgcn_mfma_f32_16x16x32_bf16(kf[g][0], qf0, s[g], 0, 0, 0);
            s[g] = __builtin_amdgcn_mfma_f32_16x16x32_bf16(kf[g][1], qf1, s[g], 0, 0, 0);
        }
        #pragma unroll
        for (int g = 0; g < 4; ++g) {
            const int key = kt * 64 + g * 16 + lhi * 4;
            #pragma unroll
            for (int r = 0; r < 4; ++r)
                s[g][r] = (key + r < qlim) ? s[g][r] * SC : -1e30f;
        }
        float tm = fmaxf(fmaxf(fmaxf(s[0][0], s[0][1]), fmaxf(s[0][2], s[0][3])),
                         fmaxf(fmaxf(s[1][0], s[1][1]), fmaxf(s[1][2], s[1][3])));
        tm = fmaxf(tm, fmaxf(fmaxf(fmaxf(s[2][0], s[2][1]), fmaxf(s[2][2], s[2][3])),
                             fmaxf(fmaxf(s[3][0], s[3][1]), fmaxf(s[3][2], s[3][3]))));
        tm = fmaxf(tm, __shfl_xor(tm, 16));
        tm = fmaxf(tm, __shfl_xor(tm, 32));
        const float mnew = fmaxf(mrun, tm);
        const float alpha = exp2f(mrun - mnew);
        mrun = mnew;
        float rs = 0.f;
        ushort4 pk[4];
        #pragma unroll
        for (int g = 0; g < 4; ++g) {
            #pragma unroll
            for (int r = 0; r < 4; ++r) {
                const float p = exp2f(s[g][r] - mnew);
                rs += p;
                ((u16*)&pk[g])[r] = f2b(p);
            }
        }
        rs += __shfl_xor(rs, 16);
        rs += __shfl_xor(rs, 32);
        lrun = lrun * alpha + rs;
        if (lhi == 0) alds[w][llo] = alpha;
        #pragma unroll
        for (int g = 0; g < 4; ++g) {
            const int chw = (g * 2 + (lhi >> 1)) ^ (llo & 7);
            *(ushort4*)((char*)&plds[w][0][0] + llo * 128 + chw * 16 + (lhi & 1) * 8) = pk[g];
        }
        const float4 av = *(const float4*)&alds[w][lhi * 4];
        #pragma unroll
        for (int g = 0; g < 4; ++g) {
            o[g][0] *= av.x; o[g][1] *= av.y; o[g][2] *= av.z; o[g][3] *= av.w;
        }
        #pragma unroll
        for (int ks = 0; ks < 2; ++ks) {
            const int chr = (ks * 4 + lhi) ^ (llo & 7);
            bf16x8 pa = *(const bf16x8*)((const char*)&plds[w][0][0] + llo * 128 + chr * 16);
            #pragma unroll
            for (int g = 0; g < 4; ++g)
                o[g] = __builtin_amdgcn_mfma_f32_16x16x32_bf16(pa, vf[g][ks], o[g], 0, 0, 0);
        }
        __builtin_amdgcn_sched_barrier(0);
        __builtin_amdgcn_s_barrier();
    }

    if (lhi == 0) llds[w][llo] = 1.f / lrun;
    __builtin_amdgcn_s_waitcnt(0);
    const float4 linv = *(const float4*)&llds[w][lhi * 4];
    #pragma unroll
    for (int g = 0; g < 4; ++g) {
        const int d = h * 64 + g * 16 + llo;
        #pragma unroll
        for (int r = 0; r < 4; ++r) {
            const int qq = qrow0 + lhi * 4 + r;
            out[(size_t)(b * TS + qq) * 512 + d] = f2b(o[g][r] * ((const float*)&linv)[r]);
        }
    }
}

// ---------------------------------------------------------------------------
// LayerNorm over F=512, bf16 in -> bf16 out; optional fused row-dot.
// ---------------------------------------------------------------------------
__global__ __launch_bounds__(256) void k_ln(
    const u16* __restrict__ in, const float* __restrict__ gam,
    const float* __restrict__ bet, u16* __restrict__ o16,
    const float* __restrict__ dotv, float* __restrict__ dotout)
{
    const int row = blockIdx.x * 4 + (threadIdx.x >> 6);
    const int l = threadIdx.x & 63;
    bf16x8 vin = *(const bf16x8*)(in + (size_t)row * 512 + l * 8);
    float x[8];
    #pragma unroll
    for (int i = 0; i < 8; ++i) x[i] = b2f((u16)vin[i]);
    float s = x[0] + x[1] + x[2] + x[3] + x[4] + x[5] + x[6] + x[7];
    #pragma unroll
    for (int off = 32; off; off >>= 1) s += __shfl_xor(s, off);
    const float mu = s * (1.f / 512.f);
    float v = 0.f;
    #pragma unroll
    for (int i = 0; i < 8; ++i) { const float d = x[i] - mu; v += d * d; }
    #pragma unroll
    for (int off = 32; off; off >>= 1) v += __shfl_xor(v, off);
    const float rstd = rsqrtf(v * (1.f / 512.f) + 1e-5f);
    float gg[8], bb[8];
    *(float4*)&gg[0] = *(const float4*)(gam + l * 8);
    *(float4*)&gg[4] = *(const float4*)(gam + l * 8 + 4);
    *(float4*)&bb[0] = *(const float4*)(bet + l * 8);
    *(float4*)&bb[4] = *(const float4*)(bet + l * 8 + 4);
    float y[8];
    #pragma unroll
    for (int i = 0; i < 8; ++i) y[i] = (x[i] - mu) * rstd * gg[i] + bb[i];
    ushort4 pk0, pk1;
    pk0.x = f2b(y[0]); pk0.y = f2b(y[1]); pk0.z = f2b(y[2]); pk0.w = f2b(y[3]);
    pk1.x = f2b(y[4]); pk1.y = f2b(y[5]); pk1.z = f2b(y[6]); pk1.w = f2b(y[7]);
    ushort4* o16p = (ushort4*)(o16 + (size_t)row * 512 + l * 8);
    o16p[0] = pk0; o16p[1] = pk1;
    if (dotv) {
        float wa[8];
        *(float4*)&wa[0] = *(const float4*)(dotv + l * 8);
        *(float4*)&wa[4] = *(const float4*)(dotv + l * 8 + 4);
        float ds = 0.f;
        #pragma unroll
        for (int i = 0; i < 8; ++i) ds += y[i] * wa[i];
        #pragma unroll
        for (int off = 32; off; off >>= 1) ds += __shfl_xor(ds, off);
        if (l == 0) dotout[row] = ds;
    }
}

// ---------------------------------------------------------------------------
__global__ __launch_bounds__(256) void k_ptr_out(
    const float* __restrict__ wq, const float* __restrict__ wk, float* __restrict__ out)
{
    const int bi = blockIdx.x;
    const int b = bi >> 9;
    const float wki = wk[bi];
    #pragma unroll
    for (int j = threadIdx.x; j < 512; j += 256) {
        float r = 0.f;
        if (j != 0) {
            const float z = (wq[b * 512 + j] + wki) * 0.044194173824159216f;
            r = 1.f / (1.f + __expf(-z));
        }
        out[(size_t)bi * 512 + j] = r;
    }
}

// ---------------------------------------------------------------------------
extern "C" void kernel_launch(void* const* d_in, const int* in_sizes, int n_in,
                              void* d_out, int out_size, void* d_ws, size_t ws_size,
                              hipStream_t stream)
{
    const float* emb = (const float*)d_in[0];
    const int* lengths = (const int*)d_in[1];
    struct Pw {
        const float *wqkv, *bqkv, *wo, *bo, *ln1g, *ln1b, *w1, *b1, *w2, *b2, *ln2g, *ln2b;
    } pp[2];
    for (int p = 0; p < 2; ++p) {
        const int base = 2 + p * 12;
        pp[p].wqkv = (const float*)d_in[base + 0];
        pp[p].bqkv = (const float*)d_in[base + 1];
        pp[p].wo   = (const float*)d_in[base + 2];
        pp[p].bo   = (const float*)d_in[base + 3];
        pp[p].ln1g = (const float*)d_in[base + 4];
        pp[p].ln1b = (const float*)d_in[base + 5];
        pp[p].w1   = (const float*)d_in[base + 6];
        pp[p].b1   = (const float*)d_in[base + 7];
        pp[p].w2   = (const float*)d_in[base + 8];
        pp[p].b2   = (const float*)d_in[base + 9];
        pp[p].ln2g = (const float*)d_in[base + 10];
        pp[p].ln2b = (const float*)d_in[base + 11];
    }
    const float* pwq = (const float*)d_in[26];
    const float* pwk = (const float*)d_in[27];

    char* ws = (char*)d_ws;
    auto alloc = [&](size_t bytes) {
        char* p = ws;
        ws += (bytes + 255) & ~(size_t)255;
        return p;
    };
    u16* wqkvT[2], *woT[2], *w1T[2], *w2T[2];
    for (int p = 0; p < 2; ++p) {
        wqkvT[p] = (u16*)alloc((size_t)TL * 1536 * 512 * 2);
        woT[p]   = (u16*)alloc((size_t)TL * 512 * 512 * 2);
        w1T[p]   = (u16*)alloc((size_t)TL * 2048 * 512 * 2);
        w2T[p]   = (u16*)alloc((size_t)TL * 512 * 2048 * 2);
    }
    const size_t MR = (size_t)TB * TS;  // 8192 rows
    u16*   emb16 = (u16*)alloc(MR * 512 * 2);
    u16*   x16   = (u16*)alloc(MR * 512 * 2);
    u16*   mem16 = (u16*)alloc(MR * 512 * 2);
    u16*   pre16 = (u16*)alloc(MR * 512 * 2);
    u16*   qbuf  = (u16*)alloc(MR * 512 * 2);
    u16*   kcb   = (u16*)alloc((size_t)TB * TH * 512 * 64 * 2);
    u16*   vtb   = (u16*)alloc((size_t)TB * TH * 64 * 512 * 2);
    u16*   att16 = (u16*)alloc(MR * 512 * 2);
    u16*   h16   = (u16*)alloc(MR * 2048 * 2);
    float* wqb   = (float*)alloc(MR * 4);
    float* wkb   = (float*)alloc(MR * 4);

    for (int p = 0; p < 2; ++p) {
        k_transpose_w<<<dim3(16, 16, 9), 256, 0, stream>>>(pp[p].wqkv, wqkvT[p], 512, 512);
        k_transpose_w<<<dim3(16, 16, 3), 256, 0, stream>>>(pp[p].wo, woT[p], 512, 512);
        k_transpose_w<<<dim3(64, 16, 3), 256, 0, stream>>>(pp[p].w1, w1T[p], 512, 2048);
        k_transpose_w<<<dim3(16, 64, 3), 256, 0, stream>>>(pp[p].w2, w2T[p], 2048, 512);
    }

    const int n4 = (int)(MR * 512 / 4);
    k_cvt<<<4096, 256, 0, stream>>>(emb, emb16, n4);

    // ---------------- encoder ----------------
    for (int i = 0; i < TL; ++i) {
        const u16* xin = (i == 0) ? emb16 : x16;
        k_gf<3><<<dim3(6, 64), 512, 0, stream>>>(
            xin, xin, 1536, wqkvT[0] + (size_t)i * 1536 * 512, pp[0].bqkv + i * 1536,
            qbuf, kcb, vtb, 1536, 512, 1536, 0);
        k_attn<0><<<dim3(8, 128), 256, 0, stream>>>(qbuf, kcb, vtb, lengths, att16);
        k_g8<2, 128, 128><<<dim3(4, 64), 512, 0, stream>>>(
            att16, woT[0] + (size_t)i * 512 * 512, pp[0].bo + i * 512,
            xin, pre16, 512, 512, 512, 0);
        k_ln<<<2048, 256, 0, stream>>>(pre16, pp[0].ln1g + i * 512, pp[0].ln1b + i * 512,
                                       x16, nullptr, nullptr);
        k_g8<1, 256, 256><<<dim3(8, 32), 512, 0, stream>>>(
            x16, w1T[0] + (size_t)i * 2048 * 512, pp[0].b1 + i * 2048,
            nullptr, h16, 2048, 512, 2048, 0);
        k_g8<2, 128, 128><<<dim3(4, 64), 512, 0, stream>>>(
            h16, w2T[0] + (size_t)i * 512 * 2048, pp[0].b2 + i * 512,
            x16, pre16, 512, 2048, 512, 0);
        if (i == TL - 1)
            k_ln<<<2048, 256, 0, stream>>>(pre16, pp[0].ln2g + i * 512, pp[0].ln2b + i * 512,
                                           mem16, pwk, wkb);
        else
            k_ln<<<2048, 256, 0, stream>>>(pre16, pp[0].ln2g + i * 512, pp[0].ln2b + i * 512,
                                           x16, nullptr, nullptr);
    }

    // ---------------- decoder ----------------
    for (int i = 0; i < TL; ++i) {
        const u16* yin = (i == 0) ? emb16 : x16;
        k_gf<3><<<dim3(6, 64), 512, 0, stream>>>(
            yin, mem16, 512, wqkvT[1] + (size_t)i * 1536 * 512, pp[1].bqkv + i * 1536,
            qbuf, kcb, vtb, 1536, 512, 1536, 0);
        k_attn<1><<<dim3(8, 128), 256, 0, stream>>>(qbuf, kcb, vtb, lengths, att16);
        k_g8<2, 128, 128><<<dim3(4, 64), 512, 0, stream>>>(
            att16, woT[1] + (size_t)i * 512 * 512, pp[1].bo + i * 512,
            yin, pre16, 512, 512, 512, 0);
        k_ln<<<2048, 256, 0, stream>>>(pre16, pp[1].ln1g + i * 512, pp[1].ln1b + i * 512,
                                       x16, nullptr, nullptr);
        k_g8<1, 256, 256><<<dim3(8, 32), 512, 0, stream>>>(
            x16, w1T[1] + (size_t)i * 2048 * 512, pp[1].b1 + i * 2048,
            nullptr, h16, 2048, 512, 2048, 0);
        k_g8<2, 128, 128><<<dim3(4, 64), 512, 0, stream>>>(
            h16, w2T[1] + (size_t)i * 512 * 2048, pp[1].b2 + i * 512,
            x16, pre16, 512, 2048, 512, 0);
        if (i == TL - 1)
            k_ln<<<2048, 256, 0, stream>>>(pre16, pp[1].ln2g + i * 512, pp[1].ln2b + i * 512,
                                           x16, pwq, wqb);
        else
            k_ln<<<2048, 256, 0, stream>>>(pre16, pp[1].ln2g + i * 512, pp[1].ln2b + i * 512,
                                           x16, nullptr, nullptr);
    }

    // ---------------- pointer head ----------------
    k_ptr_out<<<TB * TS, 256, 0, stream>>>(wqb, wkb, (float*)d_out);
}

// Round 15
// 837.923 us; speedup vs baseline: 1.2857x; 1.0042x over previous
//
#include <hip/hip_runtime.h>
#include <hip/hip_bf16.h>
#include <math.h>

#define TB 16
#define TS 512
#define TF 512
#define TH 8
#define TFF 2048
#define TL 3

typedef unsigned short u16;
typedef short bf16x8 __attribute__((ext_vector_type(8)));
typedef float f32x4 __attribute__((ext_vector_type(4)));

__device__ __forceinline__ u16 f2b(float f) {
    __hip_bfloat16 h = __float2bfloat16(f);
    return *reinterpret_cast<u16*>(&h);
}
__device__ __forceinline__ float b2f(u16 u) {
    unsigned int v = ((unsigned int)u) << 16;
    return __builtin_bit_cast(float, v);
}
// tanh-form GELU via single exp2; max |diff| vs exact erf-GELU ~3e-4.
__device__ __forceinline__ float gelu_t(float x) {
    const float u = x + 0.044715f * x * x * x;
    return x / (1.f + exp2f(-2.3022080f * u));
}

__device__ __forceinline__ void gload_lds16(const void* g, void* l) {
    __builtin_amdgcn_global_load_lds(
        (const __attribute__((address_space(1))) unsigned int*)g,
        (__attribute__((address_space(3))) unsigned int*)l, 16, 0, 0);
}

// ---------------------------------------------------------------------------
// Batched transpose + fp32->bf16: src z matrices K x N (row-major) -> dst N x K
// ---------------------------------------------------------------------------
__global__ __launch_bounds__(256) void k_transpose_w(
    const float* __restrict__ src, u16* __restrict__ dst, int K, int N)
{
    __shared__ float tile[32][33];
    const int z = blockIdx.z;
    src += (size_t)z * K * N;
    dst += (size_t)z * K * N;
    const int n0 = blockIdx.x * 32, k0 = blockIdx.y * 32;
    const int tx = threadIdx.x & 31, ty = threadIdx.x >> 5;  // 32 x 8
    #pragma unroll
    for (int i = 0; i < 32; i += 8)
        tile[ty + i][tx] = src[(size_t)(k0 + ty + i) * N + n0 + tx];
    __syncthreads();
    #pragma unroll
    for (int i = 0; i < 32; i += 8)
        dst[(size_t)(n0 + ty + i) * K + k0 + tx] = f2b(tile[tx][ty + i]);
}

// ---------------------------------------------------------------------------
// fp32 -> bf16 convert (vectorized by 4)
// ---------------------------------------------------------------------------
__global__ __launch_bounds__(256) void k_cvt(
    const float* __restrict__ src, u16* __restrict__ d16, int n4)
{
    const int i = blockIdx.x * 256 + threadIdx.x;
    if (i >= n4) return;
    float4 v = ((const float4*)src)[i];
    ushort4 p;
    p.x = f2b(v.x); p.y = f2b(v.y); p.z = f2b(v.z); p.w = f2b(v.w);
    ((ushort4*)d16)[i] = p;
}

// ---------------------------------------------------------------------------
// QKV GEMM (fine-phase): BM=128 x BN=256, BK=64, 8 waves (2x4),
// 3-buffer LDS rotation, counted vmcnt(6) gate, stage(t+2) after gate barrier.
// EPI 3: scatter q/k; V via wave-local LDS-bounce transpose.
// ---------------------------------------------------------------------------
template<int EPI>
__global__ __launch_bounds__(512, 1) void k_gf(
    const u16* __restrict__ A, const u16* __restrict__ A2, int asplit,
    const u16* __restrict__ BT,
    const float* __restrict__ bias,
    u16* __restrict__ outb,
    u16* __restrict__ out_k, u16* __restrict__ out_v,
    int N, int K, int ldo, int coloff)
{
    constexpr int BN = 256;
    constexpr int NFB = 4;
    __shared__ __align__(16) u16 SH[3 * 128 * 64 + 3 * BN * 64];
    u16* Asm = SH;
    u16* Bsm = SH + 3 * 128 * 64;

    const int gx = gridDim.x;
    int bid = blockIdx.y * gx + blockIdx.x;
    const int cpx = (gx * gridDim.y) >> 3;
    bid = (bid & 7) * cpx + (bid >> 3);
    const int bn = bid % gx, bm = bid / gx;

    const int t = threadIdx.x;
    const int w = t >> 6, l = t & 63;
    const int wm = w >> 2, wn = w & 3;
    const int lhi = l >> 4, llo = l & 15;

    f32x4 acc[4][NFB];
    #pragma unroll
    for (int m = 0; m < 4; ++m)
        #pragma unroll
        for (int n = 0; n < NFB; ++n)
            acc[m][n] = f32x4{0.f, 0.f, 0.f, 0.f};

    const u16* Asrc = (bn * BN < asplit) ? A : A2;
    const int lr = l >> 3;
    const int lcz = ((l & 7) ^ lr) * 8;
    const u16* Ag = Asrc + (size_t)(bm * 128 + w * 8 + lr) * K + lcz;
    const u16* Bg = BT + (size_t)(bn * BN + w * 8 + lr) * K + lcz;

    auto stage = [&](int buf, int tt) {
        const int kofs = tt << 6;
        gload_lds16(Ag + kofs,          Asm + buf * 8192 + (w * 8) * 64);
        gload_lds16(Ag + 64 * K + kofs, Asm + buf * 8192 + (64 + w * 8) * 64);
        #pragma unroll
        for (int i = 0; i < 4; ++i)
            gload_lds16(Bg + (size_t)i * 64 * K + kofs,
                        Bsm + buf * (BN * 64) + (i * 64 + w * 8) * 64);
    };

    const int NT = K >> 6;
    stage(0, 0);
    stage(1, 1);
    int cur = 0;
    for (int tt = 0; tt < NT; ++tt) {
        if (tt + 1 < NT) asm volatile("s_waitcnt vmcnt(6)" ::: "memory");
        else             asm volatile("s_waitcnt vmcnt(0)" ::: "memory");
        __builtin_amdgcn_s_barrier();
        __builtin_amdgcn_sched_barrier(0);
        if (tt + 2 < NT) {
            int nb = cur + 2; if (nb >= 3) nb -= 3;
            stage(nb, tt + 2);
        }

        const u16* Ab = Asm + cur * 8192;
        const u16* Bb = Bsm + cur * (BN * 64);
        bf16x8 af[4][2], bfr[NFB][2];

        #pragma unroll
        for (int kk = 0; kk < 2; ++kk) {
            #pragma unroll
            for (int mh = 0; mh < 2; ++mh) {
                #pragma unroll
                for (int mi = 0; mi < 2; ++mi) {
                    const int m = mh * 2 + mi;
                    const int row = wm * 64 + m * 16 + llo;
                    const int x = row & 7;
                    af[m][kk] = *(const bf16x8*)(Ab + row * 64 + ((kk * 4 + lhi) ^ x) * 8);
                }
                if (mh == 0) {
                    #pragma unroll
                    for (int n = 0; n < NFB; ++n) {
                        const int row = wn * 64 + n * 16 + llo;
                        const int x = row & 7;
                        bfr[n][kk] = *(const bf16x8*)(Bb + row * 64 + ((kk * 4 + lhi) ^ x) * 8);
                    }
                }
                __builtin_amdgcn_s_barrier();
                asm volatile("s_waitcnt lgkmcnt(0)" ::: "memory");
                __builtin_amdgcn_sched_barrier(0);
                __builtin_amdgcn_s_setprio(1);
                #pragma unroll
                for (int mi = 0; mi < 2; ++mi) {
                    const int m = mh * 2 + mi;
                    #pragma unroll
                    for (int n = 0; n < NFB; ++n)
                        acc[m][n] = __builtin_amdgcn_mfma_f32_16x16x32_bf16(
                            af[m][kk], bfr[n][kk], acc[m][n], 0, 0, 0);
                }
                __builtin_amdgcn_s_setprio(0);
                __builtin_amdgcn_sched_barrier(0);
            }
        }
        ++cur; if (cur >= 3) cur = 0;
    }

    const int colb = bn * BN + wn * 64;
    const int rowb = bm * 128 + wm * 64 + lhi * 4;
    const int c0w = coloff + colb;

    if constexpr (EPI == 3) {
        if (c0w >= 1024) {
            __builtin_amdgcn_s_barrier();   // all waves done reading LDS
            u16* tb = SH + w * 4096;
            #pragma unroll
            for (int n = 0; n < 4; ++n) {
                const int dl = n * 16 + llo;
                const float bv = bias[colb + n * 16 + llo];
                #pragma unroll
                for (int m = 0; m < 4; ++m) {
                    ushort4 pk;
                    #pragma unroll
                    for (int r = 0; r < 4; ++r)
                        ((u16*)&pk)[r] = f2b(acc[m][n][r] + bv);
                    const int slc = m * 2 + (lhi >> 1);
                    const int addr = dl * 64 + ((slc ^ (dl & 7)) << 3) + ((lhi & 1) << 2);
                    *(ushort4*)(tb + addr) = pk;
                }
            }
            asm volatile("s_waitcnt lgkmcnt(0)" ::: "memory");
            __builtin_amdgcn_sched_barrier(0);
            const int sbase = bm * 128 + wm * 64;
            const int bidx = sbase >> 9;
            const int srem = sbase & 511;
            const int hh = (c0w >> 6) & 7;
            u16* vo = out_v + ((size_t)bidx * 8 + hh) * 32768 + srem;
            const int cchunk = l & 7;
            #pragma unroll
            for (int rr = 0; rr < 8; ++rr) {
                const int dl2 = (l >> 3) + rr * 8;
                const int ch = cchunk ^ (dl2 & 7);
                bf16x8 vv = *(const bf16x8*)(tb + dl2 * 64 + ch * 8);
                *(bf16x8*)(vo + (size_t)dl2 * 512 + cchunk * 8) = vv;
            }
            return;
        }
    }

    #pragma unroll
    for (int n = 0; n < NFB; ++n) {
        const int col = colb + n * 16 + llo;
        const float bv = bias[col];
        #pragma unroll
        for (int m = 0; m < 4; ++m) {
            const int row = rowb + m * 16;
            float vv[4];
            #pragma unroll
            for (int r = 0; r < 4; ++r) vv[r] = acc[m][n][r] + bv;
            const int c = coloff + col;
            if ((c >> 9) == 0) {
                #pragma unroll
                for (int r = 0; r < 4; ++r)
                    outb[(size_t)(row + r) * 512 + c] = f2b(vv[r]);
            } else {
                const int hh = (c >> 6) & 7, d = c & 63;
                #pragma unroll
                for (int r = 0; r < 4; ++r) {
                    const int rr = row + r;
                    out_k[((size_t)(rr >> 9) * 8 + hh) * 32768 + (rr & 511) * 64 + d] = f2b(vv[r]);
                }
            }
        }
    }
}

// ---------------------------------------------------------------------------
// 8-wave bf16 GEMM: tile BM x BN (256x256 or 128x128), BK=64, 2-buffer LDS,
// counted vmcnt gate, stage(t+2) after reads. OCC = min blocks/CU hint.
// ff1 (256x256, EPI 1, OCC 1) and wo/ff2 (128x128, EPI 2, OCC 2).
// ---------------------------------------------------------------------------
template<int EPI, int BM, int BN, int OCC>
__global__ __launch_bounds__(512, OCC) void k_g8(
    const u16* __restrict__ A,
    const u16* __restrict__ BT,
    const float* __restrict__ bias, const u16* __restrict__ residb,
    u16* __restrict__ outb,
    int N, int K, int ldo, int coloff)
{
    constexpr int WN  = (BM == 256) ? 2 : 4;
    constexpr int CS  = BN / WN;
    constexpr int NFB = CS / 16;
    constexpr int NLA = BM / 64, NLB = BN / 64;
    constexpr int NL  = NLA + NLB;
    __shared__ __align__(16) u16 SH[2 * BM * 64 + 2 * BN * 64];
    u16* Asm = SH;
    u16* Bsm = SH + 2 * BM * 64;

    const int gx = gridDim.x;
    int bid = blockIdx.y * gx + blockIdx.x;
    const int cpx = (gx * gridDim.y) >> 3;
    bid = (bid & 7) * cpx + (bid >> 3);
    const int bn = bid % gx, bm = bid / gx;

    const int t = threadIdx.x;
    const int w = t >> 6, l = t & 63;
    const int wm = w / WN, wn = w % WN;
    const int lhi = l >> 4, llo = l & 15;

    f32x4 acc[4][NFB];
    #pragma unroll
    for (int m = 0; m < 4; ++m)
        #pragma unroll
        for (int n = 0; n < NFB; ++n)
            acc[m][n] = f32x4{0.f, 0.f, 0.f, 0.f};

    const int lr = l >> 3;
    const int lcz = ((l & 7) ^ lr) * 8;
    const u16* Ag = A + (size_t)(bm * BM + w * 8 + lr) * K + lcz;
    const u16* Bg = BT + (size_t)(bn * BN + w * 8 + lr) * K + lcz;

    auto stage = [&](int buf, int tt) {
        const int kofs = tt << 6;
        #pragma unroll
        for (int i = 0; i < NLA; ++i)
            gload_lds16(Ag + (size_t)i * 64 * K + kofs,
                        Asm + buf * (BM * 64) + (i * 64 + w * 8) * 64);
        #pragma unroll
        for (int i = 0; i < NLB; ++i)
            gload_lds16(Bg + (size_t)i * 64 * K + kofs,
                        Bsm + buf * (BN * 64) + (i * 64 + w * 8) * 64);
    };

    const int NT = K >> 6;
    stage(0, 0);
    stage(1, 1);
    for (int tt = 0; tt < NT; ++tt) {
        const int cur = tt & 1;
        if (tt + 1 < NT) {
            if constexpr (NL == 8) asm volatile("s_waitcnt vmcnt(8)" ::: "memory");
            else                   asm volatile("s_waitcnt vmcnt(4)" ::: "memory");
        } else {
            asm volatile("s_waitcnt vmcnt(0)" ::: "memory");
        }
        __builtin_amdgcn_s_barrier();
        __builtin_amdgcn_sched_barrier(0);

        const u16* Ab = Asm + cur * (BM * 64);
        const u16* Bb = Bsm + cur * (BN * 64);
        bf16x8 af[4][2], bfr[NFB][2];
        #pragma unroll
        for (int m = 0; m < 4; ++m) {
            const int row = wm * 64 + m * 16 + llo;
            const int x = row & 7;
            af[m][0] = *(const bf16x8*)(Ab + row * 64 + ((lhi) ^ x) * 8);
            af[m][1] = *(const bf16x8*)(Ab + row * 64 + ((4 + lhi) ^ x) * 8);
        }
        #pragma unroll
        for (int n = 0; n < NFB; ++n) {
            const int row = wn * CS + n * 16 + llo;
            const int x = row & 7;
            bfr[n][0] = *(const bf16x8*)(Bb + row * 64 + ((lhi) ^ x) * 8);
            bfr[n][1] = *(const bf16x8*)(Bb + row * 64 + ((4 + lhi) ^ x) * 8);
        }
        asm volatile("s_waitcnt lgkmcnt(0)" ::: "memory");
        __builtin_amdgcn_sched_barrier(0);
        __builtin_amdgcn_s_barrier();
        if (tt + 2 < NT) stage(cur, tt + 2);
        __builtin_amdgcn_s_setprio(1);
        #pragma unroll
        for (int kk = 0; kk < 2; ++kk)
            #pragma unroll
            for (int m = 0; m < 4; ++m)
                #pragma unroll
                for (int n = 0; n < NFB; ++n)
                    acc[m][n] = __builtin_amdgcn_mfma_f32_16x16x32_bf16(
                        af[m][kk], bfr[n][kk], acc[m][n], 0, 0, 0);
        __builtin_amdgcn_s_setprio(0);
        __builtin_amdgcn_sched_barrier(0);
    }

    const int colb = bn * BN + wn * CS;
    const int rowb = bm * BM + wm * 64 + lhi * 4;
    #pragma unroll
    for (int n = 0; n < NFB; ++n) {
        const int col = colb + n * 16 + llo;
        const float bv = bias[col];
        #pragma unroll
        for (int m = 0; m < 4; ++m) {
            const int row = rowb + m * 16;
            #pragma unroll
            for (int r = 0; r < 4; ++r) {
                float v = acc[m][n][r] + bv;
                const size_t off = (size_t)(row + r) * ldo + coloff + col;
                if (EPI == 1) {
                    outb[off] = f2b(gelu_t(v));
                } else {  // EPI == 2
                    v += b2f(residb[off]);
                    outb[off] = f2b(v);
                }
            }
        }
    }
}

// ---------------------------------------------------------------------------
// Fused flash attention (unchanged).
// ---------------------------------------------------------------------------
template<int DEC>
__global__ __launch_bounds__(256) void k_attn(
    const u16* __restrict__ qb, const u16* __restrict__ kc,
    const u16* __restrict__ vtp, const int* __restrict__ lengths,
    u16* __restrict__ out)
{
    __shared__ __align__(16) u16 Ks[2][64 * 64];
    __shared__ __align__(16) u16 Vs[2][64 * 64];
    __shared__ __align__(16) u16 plds[4][16][64];
    __shared__ float alds[4][16];
    __shared__ float llds[4][16];
    const int qt = blockIdx.x;
    const int bh = blockIdx.y;
    const int b = bh >> 3;
    const int h = bh & 7;
    const int t = threadIdx.x, w = t >> 6, l = t & 63;
    const int lhi = l >> 4, llo = l & 15;
    const int len = lengths[b];
    const int qrow0 = qt * 64 + w * 16;
    const int q = qrow0 + llo;

    const u16* qp = qb + (size_t)(b * TS + q) * 512 + h * 64 + lhi * 8;
    bf16x8 qf0 = *(const bf16x8*)(qp);
    bf16x8 qf1 = *(const bf16x8*)(qp + 32);

    const u16* kb = kc  + (size_t)bh * 32768;
    const u16* vb = vtp + (size_t)bh * 32768;

    const int qlim = DEC ? min(max(q, 1), len) : len;
    const int limb = DEC ? min(qt * 64 + 63, len) : len;
    const int ktend = (limb + 63) >> 6;

    f32x4 o[4];
    #pragma unroll
    for (int g = 0; g < 4; ++g) o[g] = f32x4{0.f, 0.f, 0.f, 0.f};
    float mrun = -1e30f, lrun = 0.f;

    const float SC = 0.18033688011112042f;  // 0.125 * log2(e)

    const int sr = w * 8 + (l >> 3);
    const int sc = (((l & 7) ^ (sr & 7)) << 3);
    auto stage = [&](int buf, int ktt) {
        gload_lds16(kb + ((ktt * 64 + sr) << 6) + sc,        &Ks[buf][(w * 8) * 64]);
        gload_lds16(kb + ((ktt * 64 + 32 + sr) << 6) + sc,   &Ks[buf][(32 + w * 8) * 64]);
        gload_lds16(vb + (size_t)sr * 512 + ktt * 64 + sc,   &Vs[buf][(w * 8) * 64]);
        gload_lds16(vb + (size_t)(32 + sr) * 512 + ktt * 64 + sc, &Vs[buf][(32 + w * 8) * 64]);
    };

    stage(0, 0);
    for (int kt = 0; kt < ktend; ++kt) {
        const int cur = kt & 1;
        if (kt + 1 < ktend) {
            stage(cur ^ 1, kt + 1);
            asm volatile("s_waitcnt vmcnt(4)" ::: "memory");
        } else {
            asm volatile("s_waitcnt vmcnt(0)" ::: "memory");
        }
        __builtin_amdgcn_s_barrier();
        __builtin_amdgcn_sched_barrier(0);

        bf16x8 kf[4][2], vf[4][2];
        #pragma unroll
        for (int g = 0; g < 4; ++g) {
            const int row = g * 16 + llo;
            const int x = row & 7;
            kf[g][0] = *(const bf16x8*)&Ks[cur][row * 64 + ((lhi) ^ x) * 8];
            kf[g][1] = *(const bf16x8*)&Ks[cur][row * 64 + ((4 + lhi) ^ x) * 8];
            vf[g][0] = *(const bf16x8*)&Vs[cur][row * 64 + ((lhi) ^ x) * 8];
            vf[g][1] = *(const bf16x8*)&Vs[cur][row * 64 + ((4 + lhi) ^ x) * 8];
        }
        f32x4 s[4];
        #pragma unroll
        for (int g = 0; g < 4; ++g) {
            s[g] = f32x4{0.f, 0.f, 0.f, 0.f};
            s[g] = __builtin_amdgcn_mfma_f32_16x16x32_bf16(kf[g][0], qf0, s[g], 0, 0, 0);
            s[g] = __builtin_amdgcn_mfma_f32_16x16x32_bf16(kf[g][1], qf1, s[g], 0, 0, 0);
        }
        #pragma unroll
        for (int g = 0; g < 4; ++g) {
            const int key = kt * 64 + g * 16 + lhi * 4;
            #pragma unroll
            for (int r = 0; r < 4; ++r)
                s[g][r] = (key + r < qlim) ? s[g][r] * SC : -1e30f;
        }
        float tm = fmaxf(fmaxf(fmaxf(s[0][0], s[0][1]), fmaxf(s[0][2], s[0][3])),
                         fmaxf(fmaxf(s[1][0], s[1][1]), fmaxf(s[1][2], s[1][3])));
        tm = fmaxf(tm, fmaxf(fmaxf(fmaxf(s[2][0], s[2][1]), fmaxf(s[2][2], s[2][3])),
                             fmaxf(fmaxf(s[3][0], s[3][1]), fmaxf(s[3][2], s[3][3]))));
        tm = fmaxf(tm, __shfl_xor(tm, 16));
        tm = fmaxf(tm, __shfl_xor(tm, 32));
        const float mnew = fmaxf(mrun, tm);
        const float alpha = exp2f(mrun - mnew);
        mrun = mnew;
        float rs = 0.f;
        ushort4 pk[4];
        #pragma unroll
        for (int g = 0; g < 4; ++g) {
            #pragma unroll
            for (int r = 0; r < 4; ++r) {
                const float p = exp2f(s[g][r] - mnew);
                rs += p;
                ((u16*)&pk[g])[r] = f2b(p);
            }
        }
        rs += __shfl_xor(rs, 16);
        rs += __shfl_xor(rs, 32);
        lrun = lrun * alpha + rs;
        if (lhi == 0) alds[w][llo] = alpha;
        #pragma unroll
        for (int g = 0; g < 4; ++g) {
            const int chw = (g * 2 + (lhi >> 1)) ^ (llo & 7);
            *(ushort4*)((char*)&plds[w][0][0] + llo * 128 + chw * 16 + (lhi & 1) * 8) = pk[g];
        }
        const float4 av = *(const float4*)&alds[w][lhi * 4];
        #pragma unroll
        for (int g = 0; g < 4; ++g) {
            o[g][0] *= av.x; o[g][1] *= av.y; o[g][2] *= av.z; o[g][3] *= av.w;
        }
        #pragma unroll
        for (int ks = 0; ks < 2; ++ks) {
            const int chr = (ks * 4 + lhi) ^ (llo & 7);
            bf16x8 pa = *(const bf16x8*)((const char*)&plds[w][0][0] + llo * 128 + chr * 16);
            #pragma unroll
            for (int g = 0; g < 4; ++g)
                o[g] = __builtin_amdgcn_mfma_f32_16x16x32_bf16(pa, vf[g][ks], o[g], 0, 0, 0);
        }
        __builtin_amdgcn_sched_barrier(0);
        __builtin_amdgcn_s_barrier();
    }

    if (lhi == 0) llds[w][llo] = 1.f / lrun;
    __builtin_amdgcn_s_waitcnt(0);
    const float4 linv = *(const float4*)&llds[w][lhi * 4];
    #pragma unroll
    for (int g = 0; g < 4; ++g) {
        const int d = h * 64 + g * 16 + llo;
        #pragma unroll
        for (int r = 0; r < 4; ++r) {
            const int qq = qrow0 + lhi * 4 + r;
            out[(size_t)(b * TS + qq) * 512 + d] = f2b(o[g][r] * ((const float*)&linv)[r]);
        }
    }
}

// ---------------------------------------------------------------------------
// LayerNorm over F=512, bf16 in -> bf16 out; optional fused row-dot.
// ---------------------------------------------------------------------------
__global__ __launch_bounds__(256) void k_ln(
    const u16* __restrict__ in, const float* __restrict__ gam,
    const float* __restrict__ bet, u16* __restrict__ o16,
    const float* __restrict__ dotv, float* __restrict__ dotout)
{
    const int row = blockIdx.x * 4 + (threadIdx.x >> 6);
    const int l = threadIdx.x & 63;
    bf16x8 vin = *(const bf16x8*)(in + (size_t)row * 512 + l * 8);
    float x[8];
    #pragma unroll
    for (int i = 0; i < 8; ++i) x[i] = b2f((u16)vin[i]);
    float s = x[0] + x[1] + x[2] + x[3] + x[4] + x[5] + x[6] + x[7];
    #pragma unroll
    for (int off = 32; off; off >>= 1) s += __shfl_xor(s, off);
    const float mu = s * (1.f / 512.f);
    float v = 0.f;
    #pragma unroll
    for (int i = 0; i < 8; ++i) { const float d = x[i] - mu; v += d * d; }
    #pragma unroll
    for (int off = 32; off; off >>= 1) v += __shfl_xor(v, off);
    const float rstd = rsqrtf(v * (1.f / 512.f) + 1e-5f);
    float gg[8], bb[8];
    *(float4*)&gg[0] = *(const float4*)(gam + l * 8);
    *(float4*)&gg[4] = *(const float4*)(gam + l * 8 + 4);
    *(float4*)&bb[0] = *(const float4*)(bet + l * 8);
    *(float4*)&bb[4] = *(const float4*)(bet + l * 8 + 4);
    float y[8];
    #pragma unroll
    for (int i = 0; i < 8; ++i) y[i] = (x[i] - mu) * rstd * gg[i] + bb[i];
    ushort4 pk0, pk1;
    pk0.x = f2b(y[0]); pk0.y = f2b(y[1]); pk0.z = f2b(y[2]); pk0.w = f2b(y[3]);
    pk1.x = f2b(y[4]); pk1.y = f2b(y[5]); pk1.z = f2b(y[6]); pk1.w = f2b(y[7]);
    ushort4* o16p = (ushort4*)(o16 + (size_t)row * 512 + l * 8);
    o16p[0] = pk0; o16p[1] = pk1;
    if (dotv) {
        float wa[8];
        *(float4*)&wa[0] = *(const float4*)(dotv + l * 8);
        *(float4*)&wa[4] = *(const float4*)(dotv + l * 8 + 4);
        float ds = 0.f;
        #pragma unroll
        for (int i = 0; i < 8; ++i) ds += y[i] * wa[i];
        #pragma unroll
        for (int off = 32; off; off >>= 1) ds += __shfl_xor(ds, off);
        if (l == 0) dotout[row] = ds;
    }
}

// ---------------------------------------------------------------------------
__global__ __launch_bounds__(256) void k_ptr_out(
    const float* __restrict__ wq, const float* __restrict__ wk, float* __restrict__ out)
{
    const int bi = blockIdx.x;
    const int b = bi >> 9;
    const float wki = wk[bi];
    #pragma unroll
    for (int j = threadIdx.x; j < 512; j += 256) {
        float r = 0.f;
        if (j != 0) {
            const float z = (wq[b * 512 + j] + wki) * 0.044194173824159216f;
            r = 1.f / (1.f + __expf(-z));
        }
        out[(size_t)bi * 512 + j] = r;
    }
}

// ---------------------------------------------------------------------------
extern "C" void kernel_launch(void* const* d_in, const int* in_sizes, int n_in,
                              void* d_out, int out_size, void* d_ws, size_t ws_size,
                              hipStream_t stream)
{
    const float* emb = (const float*)d_in[0];
    const int* lengths = (const int*)d_in[1];
    struct Pw {
        const float *wqkv, *bqkv, *wo, *bo, *ln1g, *ln1b, *w1, *b1, *w2, *b2, *ln2g, *ln2b;
    } pp[2];
    for (int p = 0; p < 2; ++p) {
        const int base = 2 + p * 12;
        pp[p].wqkv = (const float*)d_in[base + 0];
        pp[p].bqkv = (const float*)d_in[base + 1];
        pp[p].wo   = (const float*)d_in[base + 2];
        pp[p].bo   = (const float*)d_in[base + 3];
        pp[p].ln1g = (const float*)d_in[base + 4];
        pp[p].ln1b = (const float*)d_in[base + 5];
        pp[p].w1   = (const float*)d_in[base + 6];
        pp[p].b1   = (const float*)d_in[base + 7];
        pp[p].w2   = (const float*)d_in[base + 8];
        pp[p].b2   = (const float*)d_in[base + 9];
        pp[p].ln2g = (const float*)d_in[base + 10];
        pp[p].ln2b = (const float*)d_in[base + 11];
    }
    const float* pwq = (const float*)d_in[26];
    const float* pwk = (const float*)d_in[27];

    char* ws = (char*)d_ws;
    auto alloc = [&](size_t bytes) {
        char* p = ws;
        ws += (bytes + 255) & ~(size_t)255;
        return p;
    };
    u16* wqkvT[2], *woT[2], *w1T[2], *w2T[2];
    for (int p = 0; p < 2; ++p) {
        wqkvT[p] = (u16*)alloc((size_t)TL * 1536 * 512 * 2);
        woT[p]   = (u16*)alloc((size_t)TL * 512 * 512 * 2);
        w1T[p]   = (u16*)alloc((size_t)TL * 2048 * 512 * 2);
        w2T[p]   = (u16*)alloc((size_t)TL * 512 * 2048 * 2);
    }
    const size_t MR = (size_t)TB * TS;  // 8192 rows
    u16*   emb16 = (u16*)alloc(MR * 512 * 2);
    u16*   x16   = (u16*)alloc(MR * 512 * 2);
    u16*   mem16 = (u16*)alloc(MR * 512 * 2);
    u16*   pre16 = (u16*)alloc(MR * 512 * 2);
    u16*   qbuf  = (u16*)alloc(MR * 512 * 2);
    u16*   kcb   = (u16*)alloc((size_t)TB * TH * 512 * 64 * 2);
    u16*   vtb   = (u16*)alloc((size_t)TB * TH * 64 * 512 * 2);
    u16*   att16 = (u16*)alloc(MR * 512 * 2);
    u16*   h16   = (u16*)alloc(MR * 2048 * 2);
    float* wqb   = (float*)alloc(MR * 4);
    float* wkb   = (float*)alloc(MR * 4);

    for (int p = 0; p < 2; ++p) {
        k_transpose_w<<<dim3(16, 16, 9), 256, 0, stream>>>(pp[p].wqkv, wqkvT[p], 512, 512);
        k_transpose_w<<<dim3(16, 16, 3), 256, 0, stream>>>(pp[p].wo, woT[p], 512, 512);
        k_transpose_w<<<dim3(64, 16, 3), 256, 0, stream>>>(pp[p].w1, w1T[p], 512, 2048);
        k_transpose_w<<<dim3(16, 64, 3), 256, 0, stream>>>(pp[p].w2, w2T[p], 2048, 512);
    }

    const int n4 = (int)(MR * 512 / 4);
    k_cvt<<<4096, 256, 0, stream>>>(emb, emb16, n4);

    // ---------------- encoder ----------------
    for (int i = 0; i < TL; ++i) {
        const u16* xin = (i == 0) ? emb16 : x16;
        k_gf<3><<<dim3(6, 64), 512, 0, stream>>>(
            xin, xin, 1536, wqkvT[0] + (size_t)i * 1536 * 512, pp[0].bqkv + i * 1536,
            qbuf, kcb, vtb, 1536, 512, 1536, 0);
        k_attn<0><<<dim3(8, 128), 256, 0, stream>>>(qbuf, kcb, vtb, lengths, att16);
        k_g8<2, 128, 128, 2><<<dim3(4, 64), 512, 0, stream>>>(
            att16, woT[0] + (size_t)i * 512 * 512, pp[0].bo + i * 512,
            xin, pre16, 512, 512, 512, 0);
        k_ln<<<2048, 256, 0, stream>>>(pre16, pp[0].ln1g + i * 512, pp[0].ln1b + i * 512,
                                       x16, nullptr, nullptr);
        k_g8<1, 256, 256, 1><<<dim3(8, 32), 512, 0, stream>>>(
            x16, w1T[0] + (size_t)i * 2048 * 512, pp[0].b1 + i * 2048,
            nullptr, h16, 2048, 512, 2048, 0);
        k_g8<2, 128, 128, 2><<<dim3(4, 64), 512, 0, stream>>>(
            h16, w2T[0] + (size_t)i * 512 * 2048, pp[0].b2 + i * 512,
            x16, pre16, 512, 2048, 512, 0);
        if (i == TL - 1)
            k_ln<<<2048, 256, 0, stream>>>(pre16, pp[0].ln2g + i * 512, pp[0].ln2b + i * 512,
                                           mem16, pwk, wkb);
        else
            k_ln<<<2048, 256, 0, stream>>>(pre16, pp[0].ln2g + i * 512, pp[0].ln2b + i * 512,
                                           x16, nullptr, nullptr);
    }

    // ---------------- decoder ----------------
    for (int i = 0; i < TL; ++i) {
        const u16* yin = (i == 0) ? emb16 : x16;
        k_gf<3><<<dim3(6, 64), 512, 0, stream>>>(
            yin, mem16, 512, wqkvT[1] + (size_t)i * 1536 * 512, pp[1].bqkv + i * 1536,
            qbuf, kcb, vtb, 1536, 512, 1536, 0);
        k_attn<1><<<dim3(8, 128), 256, 0, stream>>>(qbuf, kcb, vtb, lengths, att16);
        k_g8<2, 128, 128, 2><<<dim3(4, 64), 512, 0, stream>>>(
            att16, woT[1] + (size_t)i * 512 * 512, pp[1].bo + i * 512,
            yin, pre16, 512, 512, 512, 0);
        k_ln<<<2048, 256, 0, stream>>>(pre16, pp[1].ln1g + i * 512, pp[1].ln1b + i * 512,
                                       x16, nullptr, nullptr);
        k_g8<1, 256, 256, 1><<<dim3(8, 32), 512, 0, stream>>>(
            x16, w1T[1] + (size_t)i * 2048 * 512, pp[1].b1 + i * 2048,
            nullptr, h16, 2048, 512, 2048, 0);
        k_g8<2, 128, 128, 2><<<dim3(4, 64), 512, 0, stream>>>(
            h16, w2T[1] + (size_t)i * 512 * 2048, pp[1].b2 + i * 512,
            x16, pre16, 512, 2048, 512, 0);
        if (i == TL - 1)
            k_ln<<<2048, 256, 0, stream>>>(pre16, pp[1].ln2g + i * 512, pp[1].ln2b + i * 512,
                                           x16, pwq, wqb);
        else
            k_ln<<<2048, 256, 0, stream>>>(pre16, pp[1].ln2g + i * 512, pp[1].ln2b + i * 512,
                                           x16, nullptr, nullptr);
    }

    // ---------------- pointer head ----------------
    k_ptr_out<<<TB * TS, 256, 0, stream>>>(wqb, wkb, (float*)d_out);
}